// Round 1
// baseline (4930.454 us; speedup 1.0000x reference)
//
#include <hip/hip_runtime.h>

#define NN 74240      // nodes
#define NE 593920     // edges
#define DIN 75
#define DD 128
#define NL 3
#define EPS 1e-5f

// ---------------- init GEMM: h = X @ W_init  ([NN,75] @ [75,128]) ----------------
// 1 wave per block, 64 rows/block, lane = row. X rows staged in LDS (pad 77: (lane*77+k)%32 = (lane*13+k)%32, gcd(13,32)=1 -> 2-way, free).
__global__ __launch_bounds__(64) void k_init(const float* __restrict__ X,
                                             const float* __restrict__ W,
                                             float* __restrict__ h) {
    __shared__ float sX[64 * 77];
    const int r0 = blockIdx.x * 64;
    const int lane = threadIdx.x;
    const float* Xb = X + (size_t)r0 * DIN;
    for (int e = lane; e < 64 * DIN; e += 64) {
        int r = e / DIN;
        int k = e - r * DIN;
        sX[r * 77 + k] = Xb[e];
    }
    __syncthreads();
    float* hrow = h + (size_t)(r0 + lane) * DD;
    const float* xr = &sX[lane * 77];
    for (int ct = 0; ct < 8; ++ct) {
        const int c0 = ct * 16;
        float acc[16];
        #pragma unroll
        for (int j = 0; j < 16; ++j) acc[j] = 0.0f;
        #pragma unroll 5
        for (int k = 0; k < DIN; ++k) {
            const float a = xr[k];
            const float* wk = W + k * DD + c0;   // wave-uniform -> s_load
            #pragma unroll
            for (int j = 0; j < 16; ++j)
                acc[j] = fmaf(a, wk[j], acc[j]);
        }
        #pragma unroll
        for (int j = 0; j < 16; ++j) hrow[c0 + j] = acc[j];
    }
}

// ---------------- edge scatter: agg[dst] += h[src] ----------------
// 32 lanes x float4 per edge; coalesced 512B gather; 4 fp32 global atomics per thread.
__global__ __launch_bounds__(256) void k_scatter(const float* __restrict__ h,
                                                 const int* __restrict__ src,
                                                 const int* __restrict__ dst,
                                                 float* agg) {
    const int t = blockIdx.x * 256 + threadIdx.x;   // grid sized to exactly NE*32
    const int e = t >> 5;
    const int q = (t & 31) * 4;
    const int s = src[e];
    const int d = dst[e];
    const float4 v = *(const float4*)(h + (size_t)s * DD + q);
    float* ap = agg + (size_t)d * DD + q;
    atomicAdd(ap + 0, v.x);
    atomicAdd(ap + 1, v.y);
    atomicAdd(ap + 2, v.z);
    atomicAdd(ap + 3, v.w);
}

// ---------------- fused layer GEMMs: h2 = relu(agg@Wg+bg) + relu(h@Wr+br), + BN partial sums --------
// block=256 (4 waves), 64 rows/block shared by all waves; wave w handles cols [w*32, w*32+32).
// lane = row. LDS pad 129 -> bank (lane+k)%32, 2-way free. W loads wave-uniform -> SMEM.
// h2 written into the agg buffer (row-local, safe).
__global__ __launch_bounds__(256, 2) void k_layer(const float* __restrict__ hin,
                                                  const float* aggin,
                                                  const float* __restrict__ Wg,
                                                  const float* __restrict__ bg,
                                                  const float* __restrict__ Wr,
                                                  const float* __restrict__ br,
                                                  float* h2out,
                                                  float* sums) {
    __shared__ float sA[64 * 129];
    __shared__ float sH[64 * 129];
    const int tid = threadIdx.x;
    const int r0 = blockIdx.x * 64;
    {
        const float4* A4 = (const float4*)(aggin + (size_t)r0 * DD);
        const float4* H4 = (const float4*)(hin + (size_t)r0 * DD);
        #pragma unroll
        for (int i = 0; i < 8; ++i) {
            const int idx4 = tid + i * 256;   // 0..2047
            const int base = idx4 * 4;
            const int r = base >> 7;
            const int k = base & 127;
            const float4 a = A4[idx4];
            const float4 hh = H4[idx4];
            float* pa = &sA[r * 129 + k];
            pa[0] = a.x; pa[1] = a.y; pa[2] = a.z; pa[3] = a.w;
            float* ph = &sH[r * 129 + k];
            ph[0] = hh.x; ph[1] = hh.y; ph[2] = hh.z; ph[3] = hh.w;
        }
    }
    __syncthreads();
    const int wave = tid >> 6;
    const int lane = tid & 63;
    const int row = r0 + lane;
    const float* sArow = &sA[lane * 129];
    const float* sHrow = &sH[lane * 129];

    for (int ct = 0; ct < 2; ++ct) {
        const int c0 = wave * 32 + ct * 16;
        float accg[16], accr[16];
        #pragma unroll
        for (int j = 0; j < 16; ++j) { accg[j] = 0.0f; accr[j] = 0.0f; }
        #pragma unroll 4
        for (int k = 0; k < DD; ++k) {
            const float a = sArow[k];
            const float hh = sHrow[k];
            const float* wgk = Wg + k * DD + c0;   // wave-uniform
            const float* wrk = Wr + k * DD + c0;
            #pragma unroll
            for (int j = 0; j < 16; ++j) {
                accg[j] = fmaf(a, wgk[j], accg[j]);
                accr[j] = fmaf(hh, wrk[j], accr[j]);
            }
        }
        float* outrow = h2out + (size_t)row * DD + c0;
        #pragma unroll
        for (int j = 0; j < 16; ++j) {
            float g = accg[j] + bg[c0 + j];
            g = fmaxf(g, 0.0f);
            float rr = accr[j] + br[c0 + j];
            rr = fmaxf(rr, 0.0f);
            const float v = g + rr;
            outrow[j] = v;
            float s = v, s2 = v * v;
            #pragma unroll
            for (int off = 32; off > 0; off >>= 1) {
                s += __shfl_xor(s, off, 64);
                s2 += __shfl_xor(s2, off, 64);
            }
            accg[j] = s;   // reuse regs: wave-total of v
            accr[j] = s2;  // wave-total of v^2
        }
        if (lane == 0) {
            #pragma unroll
            for (int j = 0; j < 16; ++j) {
                atomicAdd(&sums[c0 + j], accg[j]);
                atomicAdd(&sums[DD + c0 + j], accr[j]);
            }
        }
    }
}

// ---------------- BatchNorm normalize ----------------
__global__ __launch_bounds__(256) void k_bn(const float* __restrict__ h2,
                                            const float* __restrict__ sums,
                                            const float* __restrict__ gamma,
                                            const float* __restrict__ beta,
                                            float* __restrict__ out) {
    const int t = blockIdx.x * 256 + threadIdx.x;  // NN*32 threads
    const size_t base = (size_t)t * 4;
    const int c = (int)(base & 127);
    const float4 v = *(const float4*)(h2 + base);
    const float4 s = *(const float4*)(sums + c);
    const float4 s2 = *(const float4*)(sums + DD + c);
    const float4 g = *(const float4*)(gamma + c);
    const float4 b = *(const float4*)(beta + c);
    const float invN = 1.0f / (float)NN;
    float4 o;
    {
        float mu = s.x * invN; float var = s2.x * invN - mu * mu;
        o.x = (v.x - mu) * (g.x * rsqrtf(var + EPS)) + b.x;
    }
    {
        float mu = s.y * invN; float var = s2.y * invN - mu * mu;
        o.y = (v.y - mu) * (g.y * rsqrtf(var + EPS)) + b.y;
    }
    {
        float mu = s.z * invN; float var = s2.z * invN - mu * mu;
        o.z = (v.z - mu) * (g.z * rsqrtf(var + EPS)) + b.z;
    }
    {
        float mu = s.w * invN; float var = s2.w * invN - mu * mu;
        o.w = (v.w - mu) * (g.w * rsqrtf(var + EPS)) + b.w;
    }
    *(float4*)(out + base) = o;
}

extern "C" void kernel_launch(void* const* d_in, const int* in_sizes, int n_in,
                              void* d_out, int out_size, void* d_ws, size_t ws_size,
                              hipStream_t stream) {
    const float* X     = (const float*)d_in[0];
    const int*   src   = (const int*)d_in[1];
    const int*   dst   = (const int*)d_in[2];
    const float* Wi    = (const float*)d_in[3];
    const float* Wg    = (const float*)d_in[4];
    const float* bg    = (const float*)d_in[5];
    const float* Wr    = (const float*)d_in[6];
    const float* br    = (const float*)d_in[7];
    const float* gamma = (const float*)d_in[8];
    const float* beta  = (const float*)d_in[9];
    float* out = (float*)d_out;

    float* h    = (float*)d_ws;                       // [NN*DD]
    float* agg  = h + (size_t)NN * DD;                // [NN*DD], reused as h2
    float* sums = agg + (size_t)NN * DD;              // [NL * 2 * DD]

    hipMemsetAsync(sums, 0, NL * 2 * DD * sizeof(float), stream);
    k_init<<<NN / 64, 64, 0, stream>>>(X, Wi, h);

    for (int l = 0; l < NL; ++l) {
        hipMemsetAsync(agg, 0, (size_t)NN * DD * sizeof(float), stream);
        k_scatter<<<(NE * 32) / 256, 256, 0, stream>>>(h, src, dst, agg);
        k_layer<<<NN / 64, 256, 0, stream>>>(h, agg, Wg + l * DD * DD, bg + l * DD,
                                             Wr + l * DD * DD, br + l * DD,
                                             agg, sums + l * 2 * DD);
        float* outp = (l == NL - 1) ? out : h;
        k_bn<<<(NN * 32) / 256, 256, 0, stream>>>(agg, sums + l * 2 * DD,
                                                  gamma + l * DD, beta + l * DD, outp);
    }
}

// Round 2
// 2430.520 us; speedup vs baseline: 2.0286x; 2.0286x over previous
//
#include <hip/hip_runtime.h>

#define NN 74240      // nodes
#define NE 593920     // edges
#define DIN 75
#define DD 128
#define NL 3
#define EPS 1e-5f

// ---------------- init GEMM: h = X @ W_init  ([NN,75] @ [75,128]) ----------------
__global__ __launch_bounds__(64) void k_init(const float* __restrict__ X,
                                             const float* __restrict__ W,
                                             float* __restrict__ h) {
    __shared__ float sX[64 * 77];
    const int r0 = blockIdx.x * 64;
    const int lane = threadIdx.x;
    const float* Xb = X + (size_t)r0 * DIN;
    for (int e = lane; e < 64 * DIN; e += 64) {
        int r = e / DIN;
        int k = e - r * DIN;
        sX[r * 77 + k] = Xb[e];
    }
    __syncthreads();
    float* hrow = h + (size_t)(r0 + lane) * DD;
    const float* xr = &sX[lane * 77];
    for (int ct = 0; ct < 8; ++ct) {
        const int c0 = ct * 16;
        float acc[16];
        #pragma unroll
        for (int j = 0; j < 16; ++j) acc[j] = 0.0f;
        #pragma unroll 5
        for (int k = 0; k < DIN; ++k) {
            const float a = xr[k];
            const float* wk = W + k * DD + c0;   // wave-uniform -> s_load
            #pragma unroll
            for (int j = 0; j < 16; ++j)
                acc[j] = fmaf(a, wk[j], acc[j]);
        }
        #pragma unroll
        for (int j = 0; j < 16; ++j) hrow[c0 + j] = acc[j];
    }
}

// ---------------- CSR build: histogram -> scan -> fill ----------------
__global__ __launch_bounds__(256) void k_hist(const int* __restrict__ dst, int* cnt) {
    const int e = blockIdx.x * 256 + threadIdx.x;   // grid == NE
    atomicAdd(&cnt[dst[e]], 1);
}

__global__ __launch_bounds__(1024) void k_scan(const int* __restrict__ cnt,
                                               int* __restrict__ rowptr,
                                               int* __restrict__ offs) {
    __shared__ int sdata[1024];
    const int t = threadIdx.x;
    const int i0 = t * 73;
    const int i1 = (i0 + 73 < NN) ? (i0 + 73) : NN;
    int p = 0;
    for (int i = i0; i < i1; ++i) p += cnt[i];
    sdata[t] = p;
    __syncthreads();
    for (int off = 1; off < 1024; off <<= 1) {
        int v = (t >= off) ? sdata[t - off] : 0;
        __syncthreads();
        sdata[t] += v;
        __syncthreads();
    }
    int run = (t > 0) ? sdata[t - 1] : 0;
    for (int i = i0; i < i1; ++i) {
        rowptr[i] = run;
        offs[i] = run;
        run += cnt[i];
    }
    if (t == 0) rowptr[NN] = NE;
}

__global__ __launch_bounds__(256) void k_fill(const int* __restrict__ src,
                                              const int* __restrict__ dst,
                                              int* offs, int* __restrict__ col) {
    const int e = blockIdx.x * 256 + threadIdx.x;   // grid == NE
    const int pos = atomicAdd(&offs[dst[e]], 1);
    col[pos] = src[e];
}

// ---------------- fused layer: CSR gather + dual GEMM + ReLU + BN partial sums ----
// block=256 (4 waves), 64 rows/block. Wave w gathers rows [w*16, w*16+16) into sA
// (float2 loads over h, wave-uniform col -> s_load), all threads stage sH.
// Compute: wave w handles cols [w*32, w*32+32), lane = row. Pad 129: 2-way, free.
__global__ __launch_bounds__(256, 2) void k_layer(const float* __restrict__ hin,
                                                  const int* __restrict__ rowptr,
                                                  const int* __restrict__ col,
                                                  const float* __restrict__ Wg,
                                                  const float* __restrict__ bg,
                                                  const float* __restrict__ Wr,
                                                  const float* __restrict__ br,
                                                  float* __restrict__ h2out,
                                                  float* sums) {
    __shared__ float sA[64 * 129];
    __shared__ float sH[64 * 129];
    const int tid = threadIdx.x;
    const int r0 = blockIdx.x * 64;
    const int wave = tid >> 6;
    const int lane = tid & 63;

    // stage sH (residual input) with float4 global loads
    {
        const float4* H4 = (const float4*)(hin + (size_t)r0 * DD);
        #pragma unroll
        for (int i = 0; i < 8; ++i) {
            const int idx4 = tid + i * 256;
            const int base = idx4 * 4;
            const int r = base >> 7;
            const int k = base & 127;
            const float4 hh = H4[idx4];
            float* ph = &sH[r * 129 + k];
            ph[0] = hh.x; ph[1] = hh.y; ph[2] = hh.z; ph[3] = hh.w;
        }
    }
    // gather: wave w accumulates in-neighbors for its 16 rows
    {
        const int lr0 = wave * 16;
        for (int lr = lr0; lr < lr0 + 16; ++lr) {
            const int row = r0 + lr;
            const int eb = rowptr[row];       // wave-uniform
            const int ee = rowptr[row + 1];
            float a0 = 0.0f, a1 = 0.0f;
            for (int e = eb; e < ee; ++e) {
                const int c = col[e];         // wave-uniform -> s_load
                const float2 v = *(const float2*)(hin + (size_t)c * DD + 2 * lane);
                a0 += v.x; a1 += v.y;
            }
            sA[lr * 129 + 2 * lane]     = a0;
            sA[lr * 129 + 2 * lane + 1] = a1;
        }
    }
    __syncthreads();

    const int row = r0 + lane;
    const float* sArow = &sA[lane * 129];
    const float* sHrow = &sH[lane * 129];

    for (int ct = 0; ct < 2; ++ct) {
        const int c0 = wave * 32 + ct * 16;
        float accg[16], accr[16];
        #pragma unroll
        for (int j = 0; j < 16; ++j) { accg[j] = 0.0f; accr[j] = 0.0f; }
        #pragma unroll 4
        for (int k = 0; k < DD; ++k) {
            const float a = sArow[k];
            const float hh = sHrow[k];
            const float* wgk = Wg + k * DD + c0;   // wave-uniform
            const float* wrk = Wr + k * DD + c0;
            #pragma unroll
            for (int j = 0; j < 16; ++j) {
                accg[j] = fmaf(a, wgk[j], accg[j]);
                accr[j] = fmaf(hh, wrk[j], accr[j]);
            }
        }
        float* outrow = h2out + (size_t)row * DD + c0;
        #pragma unroll
        for (int j = 0; j < 16; ++j) {
            float g = accg[j] + bg[c0 + j];
            g = fmaxf(g, 0.0f);
            float rr = accr[j] + br[c0 + j];
            rr = fmaxf(rr, 0.0f);
            const float v = g + rr;
            outrow[j] = v;
            float s = v, s2 = v * v;
            #pragma unroll
            for (int off = 32; off > 0; off >>= 1) {
                s += __shfl_xor(s, off, 64);
                s2 += __shfl_xor(s2, off, 64);
            }
            accg[j] = s;
            accr[j] = s2;
        }
        if (lane == 0) {
            #pragma unroll
            for (int j = 0; j < 16; ++j) {
                atomicAdd(&sums[c0 + j], accg[j]);
                atomicAdd(&sums[DD + c0 + j], accr[j]);
            }
        }
    }
}

// ---------------- BatchNorm normalize ----------------
__global__ __launch_bounds__(256) void k_bn(const float* __restrict__ h2,
                                            const float* __restrict__ sums,
                                            const float* __restrict__ gamma,
                                            const float* __restrict__ beta,
                                            float* __restrict__ out) {
    const int t = blockIdx.x * 256 + threadIdx.x;  // NN*32 threads
    const size_t base = (size_t)t * 4;
    const int c = (int)(base & 127);
    const float4 v = *(const float4*)(h2 + base);
    const float4 s = *(const float4*)(sums + c);
    const float4 s2 = *(const float4*)(sums + DD + c);
    const float4 g = *(const float4*)(gamma + c);
    const float4 b = *(const float4*)(beta + c);
    const float invN = 1.0f / (float)NN;
    float4 o;
    {
        float mu = s.x * invN; float var = s2.x * invN - mu * mu;
        o.x = (v.x - mu) * (g.x * rsqrtf(var + EPS)) + b.x;
    }
    {
        float mu = s.y * invN; float var = s2.y * invN - mu * mu;
        o.y = (v.y - mu) * (g.y * rsqrtf(var + EPS)) + b.y;
    }
    {
        float mu = s.z * invN; float var = s2.z * invN - mu * mu;
        o.z = (v.z - mu) * (g.z * rsqrtf(var + EPS)) + b.z;
    }
    {
        float mu = s.w * invN; float var = s2.w * invN - mu * mu;
        o.w = (v.w - mu) * (g.w * rsqrtf(var + EPS)) + b.w;
    }
    *(float4*)(out + base) = o;
}

extern "C" void kernel_launch(void* const* d_in, const int* in_sizes, int n_in,
                              void* d_out, int out_size, void* d_ws, size_t ws_size,
                              hipStream_t stream) {
    const float* X     = (const float*)d_in[0];
    const int*   src   = (const int*)d_in[1];
    const int*   dst   = (const int*)d_in[2];
    const float* Wi    = (const float*)d_in[3];
    const float* Wg    = (const float*)d_in[4];
    const float* bg    = (const float*)d_in[5];
    const float* Wr    = (const float*)d_in[6];
    const float* br    = (const float*)d_in[7];
    const float* gamma = (const float*)d_in[8];
    const float* beta  = (const float*)d_in[9];
    float* out = (float*)d_out;

    float* h    = (float*)d_ws;                       // [NN*DD] fp32
    float* sums = h + (size_t)NN * DD;                // [NL*2*DD]
    int* cnt    = (int*)(sums + NL * 2 * DD);         // [NN]
    int* rowptr = cnt + NN;                           // [NN+1]
    int* offs   = rowptr + NN + 1;                    // [NN]
    int* col    = offs + NN;                          // [NE]
    float* h2   = out;                                // reuse d_out as h2 scratch

    hipMemsetAsync(sums, 0, NL * 2 * DD * sizeof(float), stream);
    hipMemsetAsync(cnt, 0, NN * sizeof(int), stream);

    k_init<<<NN / 64, 64, 0, stream>>>(X, Wi, h);
    k_hist<<<NE / 256, 256, 0, stream>>>(dst, cnt);
    k_scan<<<1, 1024, 0, stream>>>(cnt, rowptr, offs);
    k_fill<<<NE / 256, 256, 0, stream>>>(src, dst, offs, col);

    for (int l = 0; l < NL; ++l) {
        k_layer<<<NN / 64, 256, 0, stream>>>(h, rowptr, col,
                                             Wg + l * DD * DD, bg + l * DD,
                                             Wr + l * DD * DD, br + l * DD,
                                             h2, sums + l * 2 * DD);
        float* outp = (l == NL - 1) ? out : h;
        k_bn<<<(NN * 32) / 256, 256, 0, stream>>>(h2, sums + l * 2 * DD,
                                                  gamma + l * DD, beta + l * DD, outp);
    }
}

// Round 3
// 2274.075 us; speedup vs baseline: 2.1681x; 1.0688x over previous
//
#include <hip/hip_runtime.h>

#define NN 74240      // nodes
#define NE 593920     // edges
#define DIN 75
#define DD 128
#define NL 3
#define EPS 1e-5f

// ---------------- init GEMM: h = X @ W_init  ([NN,75] @ [75,128]) ----------------
__global__ __launch_bounds__(64) void k_init(const float* __restrict__ X,
                                             const float* __restrict__ W,
                                             float* __restrict__ h) {
    __shared__ float sX[64 * 77];
    const int r0 = blockIdx.x * 64;
    const int lane = threadIdx.x;
    const float* Xb = X + (size_t)r0 * DIN;
    for (int e = lane; e < 64 * DIN; e += 64) {
        int r = e / DIN;
        int k = e - r * DIN;
        sX[r * 77 + k] = Xb[e];
    }
    __syncthreads();
    float* hrow = h + (size_t)(r0 + lane) * DD;
    const float* xr = &sX[lane * 77];
    for (int ct = 0; ct < 8; ++ct) {
        const int c0 = ct * 16;
        float acc[16];
        #pragma unroll
        for (int j = 0; j < 16; ++j) acc[j] = 0.0f;
        #pragma unroll 5
        for (int k = 0; k < DIN; ++k) {
            const float a = xr[k];
            const float* wk = W + k * DD + c0;   // wave-uniform -> s_load
            #pragma unroll
            for (int j = 0; j < 16; ++j)
                acc[j] = fmaf(a, wk[j], acc[j]);
        }
        #pragma unroll
        for (int j = 0; j < 16; ++j) hrow[c0 + j] = acc[j];
    }
}

// ---------------- CSR build: histogram -> scan -> fill ----------------
__global__ __launch_bounds__(256) void k_hist(const int* __restrict__ dst, int* cnt) {
    const int e = blockIdx.x * 256 + threadIdx.x;   // grid == NE
    atomicAdd(&cnt[dst[e]], 1);
}

__global__ __launch_bounds__(1024) void k_scan(const int* __restrict__ cnt,
                                               int* __restrict__ rowptr,
                                               int* __restrict__ offs) {
    __shared__ int sdata[1024];
    const int t = threadIdx.x;
    const int i0 = t * 73;
    const int i1 = (i0 + 73 < NN) ? (i0 + 73) : NN;
    int p = 0;
    for (int i = i0; i < i1; ++i) p += cnt[i];
    sdata[t] = p;
    __syncthreads();
    for (int off = 1; off < 1024; off <<= 1) {
        int v = (t >= off) ? sdata[t - off] : 0;
        __syncthreads();
        sdata[t] += v;
        __syncthreads();
    }
    int run = (t > 0) ? sdata[t - 1] : 0;
    for (int i = i0; i < i1; ++i) {
        rowptr[i] = run;
        offs[i] = run;
        run += cnt[i];
    }
    if (t == 0) rowptr[NN] = NE;
}

__global__ __launch_bounds__(256) void k_fill(const int* __restrict__ src,
                                              const int* __restrict__ dst,
                                              int* offs, int* __restrict__ col) {
    const int e = blockIdx.x * 256 + threadIdx.x;   // grid == NE
    const int pos = atomicAdd(&offs[dst[e]], 1);
    col[pos] = src[e];
}

// ---------------- gather: agg[row] = sum_{e in row} h[col[e]] ----------------
// One wave per row (massive TLP: 74240 waves). float2 per lane; edges unrolled x4
// so 4 independent 512B gathers are in flight per wave.
__global__ __launch_bounds__(256) void k_gather(const float* __restrict__ h,
                                                const int* __restrict__ rowptr,
                                                const int* __restrict__ col,
                                                float* __restrict__ agg) {
    const int wave = threadIdx.x >> 6;
    const int lane = threadIdx.x & 63;
    const int row = blockIdx.x * 4 + wave;   // grid = NN/4
    const int eb = rowptr[row];
    const int ee = rowptr[row + 1];
    const int f = 2 * lane;
    float a0x = 0.f, a0y = 0.f, a1x = 0.f, a1y = 0.f;
    float a2x = 0.f, a2y = 0.f, a3x = 0.f, a3y = 0.f;
    int e = eb;
    for (; e + 4 <= ee; e += 4) {
        const int c0 = col[e], c1 = col[e + 1], c2 = col[e + 2], c3 = col[e + 3];
        const float2 v0 = *(const float2*)(h + (size_t)c0 * DD + f);
        const float2 v1 = *(const float2*)(h + (size_t)c1 * DD + f);
        const float2 v2 = *(const float2*)(h + (size_t)c2 * DD + f);
        const float2 v3 = *(const float2*)(h + (size_t)c3 * DD + f);
        a0x += v0.x; a0y += v0.y;
        a1x += v1.x; a1y += v1.y;
        a2x += v2.x; a2y += v2.y;
        a3x += v3.x; a3y += v3.y;
    }
    for (; e < ee; ++e) {
        const int c = col[e];
        const float2 v = *(const float2*)(h + (size_t)c * DD + f);
        a0x += v.x; a0y += v.y;
    }
    float2 o;
    o.x = (a0x + a1x) + (a2x + a3x);
    o.y = (a0y + a1y) + (a2y + a3y);
    *(float2*)(agg + (size_t)row * DD + f) = o;
}

// ---------------- fused layer GEMMs: h2 = relu(agg@Wg+bg) + relu(h@Wr+br), + BN sums --------
__global__ __launch_bounds__(256, 2) void k_layer(const float* __restrict__ hin,
                                                  const float* __restrict__ aggin,
                                                  const float* __restrict__ Wg,
                                                  const float* __restrict__ bg,
                                                  const float* __restrict__ Wr,
                                                  const float* __restrict__ br,
                                                  float* __restrict__ h2out,
                                                  float* sums) {
    __shared__ float sA[64 * 129];
    __shared__ float sH[64 * 129];
    const int tid = threadIdx.x;
    const int r0 = blockIdx.x * 64;
    {
        const float4* A4 = (const float4*)(aggin + (size_t)r0 * DD);
        const float4* H4 = (const float4*)(hin + (size_t)r0 * DD);
        #pragma unroll
        for (int i = 0; i < 8; ++i) {
            const int idx4 = tid + i * 256;
            const int base = idx4 * 4;
            const int r = base >> 7;
            const int k = base & 127;
            const float4 a = A4[idx4];
            const float4 hh = H4[idx4];
            float* pa = &sA[r * 129 + k];
            pa[0] = a.x; pa[1] = a.y; pa[2] = a.z; pa[3] = a.w;
            float* ph = &sH[r * 129 + k];
            ph[0] = hh.x; ph[1] = hh.y; ph[2] = hh.z; ph[3] = hh.w;
        }
    }
    __syncthreads();
    const int wave = tid >> 6;
    const int lane = tid & 63;
    const int row = r0 + lane;
    const float* sArow = &sA[lane * 129];
    const float* sHrow = &sH[lane * 129];

    for (int ct = 0; ct < 2; ++ct) {
        const int c0 = wave * 32 + ct * 16;
        float accg[16], accr[16];
        #pragma unroll
        for (int j = 0; j < 16; ++j) { accg[j] = 0.0f; accr[j] = 0.0f; }
        #pragma unroll 4
        for (int k = 0; k < DD; ++k) {
            const float a = sArow[k];
            const float hh = sHrow[k];
            const float* wgk = Wg + k * DD + c0;   // wave-uniform
            const float* wrk = Wr + k * DD + c0;
            #pragma unroll
            for (int j = 0; j < 16; ++j) {
                accg[j] = fmaf(a, wgk[j], accg[j]);
                accr[j] = fmaf(hh, wrk[j], accr[j]);
            }
        }
        float* outrow = h2out + (size_t)row * DD + c0;
        #pragma unroll
        for (int j = 0; j < 16; ++j) {
            float g = accg[j] + bg[c0 + j];
            g = fmaxf(g, 0.0f);
            float rr = accr[j] + br[c0 + j];
            rr = fmaxf(rr, 0.0f);
            const float v = g + rr;
            outrow[j] = v;
            float s = v, s2 = v * v;
            #pragma unroll
            for (int off = 32; off > 0; off >>= 1) {
                s += __shfl_xor(s, off, 64);
                s2 += __shfl_xor(s2, off, 64);
            }
            accg[j] = s;
            accr[j] = s2;
        }
        if (lane == 0) {
            #pragma unroll
            for (int j = 0; j < 16; ++j) {
                atomicAdd(&sums[c0 + j], accg[j]);
                atomicAdd(&sums[DD + c0 + j], accr[j]);
            }
        }
    }
}

// ---------------- BatchNorm normalize ----------------
__global__ __launch_bounds__(256) void k_bn(const float* __restrict__ h2,
                                            const float* __restrict__ sums,
                                            const float* __restrict__ gamma,
                                            const float* __restrict__ beta,
                                            float* __restrict__ out) {
    const int t = blockIdx.x * 256 + threadIdx.x;  // NN*32 threads
    const size_t base = (size_t)t * 4;
    const int c = (int)(base & 127);
    const float4 v = *(const float4*)(h2 + base);
    const float4 s = *(const float4*)(sums + c);
    const float4 s2 = *(const float4*)(sums + DD + c);
    const float4 g = *(const float4*)(gamma + c);
    const float4 b = *(const float4*)(beta + c);
    const float invN = 1.0f / (float)NN;
    float4 o;
    {
        float mu = s.x * invN; float var = s2.x * invN - mu * mu;
        o.x = (v.x - mu) * (g.x * rsqrtf(var + EPS)) + b.x;
    }
    {
        float mu = s.y * invN; float var = s2.y * invN - mu * mu;
        o.y = (v.y - mu) * (g.y * rsqrtf(var + EPS)) + b.y;
    }
    {
        float mu = s.z * invN; float var = s2.z * invN - mu * mu;
        o.z = (v.z - mu) * (g.z * rsqrtf(var + EPS)) + b.z;
    }
    {
        float mu = s.w * invN; float var = s2.w * invN - mu * mu;
        o.w = (v.w - mu) * (g.w * rsqrtf(var + EPS)) + b.w;
    }
    *(float4*)(out + base) = o;
}

extern "C" void kernel_launch(void* const* d_in, const int* in_sizes, int n_in,
                              void* d_out, int out_size, void* d_ws, size_t ws_size,
                              hipStream_t stream) {
    const float* X     = (const float*)d_in[0];
    const int*   src   = (const int*)d_in[1];
    const int*   dst   = (const int*)d_in[2];
    const float* Wi    = (const float*)d_in[3];
    const float* Wg    = (const float*)d_in[4];
    const float* bg    = (const float*)d_in[5];
    const float* Wr    = (const float*)d_in[6];
    const float* br    = (const float*)d_in[7];
    const float* gamma = (const float*)d_in[8];
    const float* beta  = (const float*)d_in[9];
    float* out = (float*)d_out;

    float* h    = (float*)d_ws;                       // [NN*DD]
    float* agg  = h + (size_t)NN * DD;                // [NN*DD]
    float* sums = agg + (size_t)NN * DD;              // [NL*2*DD]
    int* rowptr = (int*)(sums + NL * 2 * DD);         // [NN+1]
    int* col    = rowptr + NN + 1;                    // [NE]
    // CSR-build scratch aliased into agg (dead once k_fill completes)
    int* cnt    = (int*)agg;                          // [NN]
    int* offs   = cnt + NN;                           // [NN]
    float* h2   = out;                                // reuse d_out as h2 scratch

    hipMemsetAsync(sums, 0, NL * 2 * DD * sizeof(float), stream);
    hipMemsetAsync(cnt, 0, NN * sizeof(int), stream);

    k_init<<<NN / 64, 64, 0, stream>>>(X, Wi, h);
    k_hist<<<NE / 256, 256, 0, stream>>>(dst, cnt);
    k_scan<<<1, 1024, 0, stream>>>(cnt, rowptr, offs);
    k_fill<<<NE / 256, 256, 0, stream>>>(src, dst, offs, col);

    for (int l = 0; l < NL; ++l) {
        k_gather<<<NN / 4, 256, 0, stream>>>(h, rowptr, col, agg);
        k_layer<<<NN / 64, 256, 0, stream>>>(h, agg,
                                             Wg + l * DD * DD, bg + l * DD,
                                             Wr + l * DD * DD, br + l * DD,
                                             h2, sums + l * 2 * DD);
        float* outp = (l == NL - 1) ? out : h;
        k_bn<<<(NN * 32) / 256, 256, 0, stream>>>(h2, sums + l * 2 * DD,
                                                  gamma + l * DD, beta + l * DD, outp);
    }
}

// Round 4
// 2205.516 us; speedup vs baseline: 2.2355x; 1.0311x over previous
//
#include <hip/hip_runtime.h>

#define NN 74240      // nodes
#define NE 593920     // edges
#define DIN 75
#define DD 128
#define NL 3
#define EPS 1e-5f

// ---------------- init GEMM: h = X @ W_init  ([NN,75] @ [75,128]) ----------------
__global__ __launch_bounds__(64) void k_init(const float* __restrict__ X,
                                             const float* __restrict__ W,
                                             float* __restrict__ h) {
    __shared__ float sX[64 * 77];
    const int r0 = blockIdx.x * 64;
    const int lane = threadIdx.x;
    const float* Xb = X + (size_t)r0 * DIN;
    for (int e = lane; e < 64 * DIN; e += 64) {
        int r = e / DIN;
        int k = e - r * DIN;
        sX[r * 77 + k] = Xb[e];
    }
    __syncthreads();
    float* hrow = h + (size_t)(r0 + lane) * DD;
    const float* xr = &sX[lane * 77];
    for (int ct = 0; ct < 8; ++ct) {
        const int c0 = ct * 16;       // compile-time uniform -> s_load path
        float acc[16];
        #pragma unroll
        for (int j = 0; j < 16; ++j) acc[j] = 0.0f;
        #pragma unroll 5
        for (int k = 0; k < DIN; ++k) {
            const float a = xr[k];
            const float* wk = W + k * DD + c0;
            #pragma unroll
            for (int j = 0; j < 16; ++j)
                acc[j] = fmaf(a, wk[j], acc[j]);
        }
        #pragma unroll
        for (int j = 0; j < 16; ++j) hrow[c0 + j] = acc[j];
    }
}

// ---------------- CSR build: histogram -> scan -> fill ----------------
__global__ __launch_bounds__(256) void k_hist(const int* __restrict__ dst, int* cnt) {
    const int e = blockIdx.x * 256 + threadIdx.x;   // grid == NE
    atomicAdd(&cnt[dst[e]], 1);
}

__global__ __launch_bounds__(1024) void k_scan(const int* __restrict__ cnt,
                                               int* __restrict__ rowptr,
                                               int* __restrict__ offs) {
    __shared__ int sdata[1024];
    const int t = threadIdx.x;
    const int i0 = t * 73;
    const int i1 = (i0 + 73 < NN) ? (i0 + 73) : NN;
    int p = 0;
    for (int i = i0; i < i1; ++i) p += cnt[i];
    sdata[t] = p;
    __syncthreads();
    for (int off = 1; off < 1024; off <<= 1) {
        int v = (t >= off) ? sdata[t - off] : 0;
        __syncthreads();
        sdata[t] += v;
        __syncthreads();
    }
    int run = (t > 0) ? sdata[t - 1] : 0;
    for (int i = i0; i < i1; ++i) {
        rowptr[i] = run;
        offs[i] = run;
        run += cnt[i];
    }
    if (t == 0) rowptr[NN] = NE;
}

__global__ __launch_bounds__(256) void k_fill(const int* __restrict__ src,
                                              const int* __restrict__ dst,
                                              int* offs, int* __restrict__ col) {
    const int e = blockIdx.x * 256 + threadIdx.x;   // grid == NE
    const int pos = atomicAdd(&offs[dst[e]], 1);
    col[pos] = src[e];
}

// ---------------- gather: agg[row] = sum_{e in row} h[col[e]] ----------------
// One wave per row. Wave split into two 32-lane halves; half p handles edges
// eb+p, eb+p+2, ... with float4/lane (128 floats = 32 lanes x float4).
// x4 unroll -> 8 independent 512B gathers in flight per wave. __shfl_xor(32)
// combines the halves at the end.
__global__ __launch_bounds__(256) void k_gather(const float* __restrict__ h,
                                                const int* __restrict__ rowptr,
                                                const int* __restrict__ col,
                                                float* __restrict__ agg) {
    const int wave = threadIdx.x >> 6;
    const int lane = threadIdx.x & 63;
    const int row = blockIdx.x * 4 + wave;   // grid = NN/4
    const int eb = rowptr[row];
    const int ee = rowptr[row + 1];
    const int half = lane >> 5;
    const int f = (lane & 31) * 4;
    float4 a0 = {0.f,0.f,0.f,0.f}, a1 = {0.f,0.f,0.f,0.f};
    float4 a2 = {0.f,0.f,0.f,0.f}, a3 = {0.f,0.f,0.f,0.f};
    int e = eb + half;
    for (; e + 6 < ee; e += 8) {
        const int c0 = col[e], c1 = col[e + 2], c2 = col[e + 4], c3 = col[e + 6];
        const float4 v0 = *(const float4*)(h + (size_t)c0 * DD + f);
        const float4 v1 = *(const float4*)(h + (size_t)c1 * DD + f);
        const float4 v2 = *(const float4*)(h + (size_t)c2 * DD + f);
        const float4 v3 = *(const float4*)(h + (size_t)c3 * DD + f);
        a0.x += v0.x; a0.y += v0.y; a0.z += v0.z; a0.w += v0.w;
        a1.x += v1.x; a1.y += v1.y; a1.z += v1.z; a1.w += v1.w;
        a2.x += v2.x; a2.y += v2.y; a2.z += v2.z; a2.w += v2.w;
        a3.x += v3.x; a3.y += v3.y; a3.z += v3.z; a3.w += v3.w;
    }
    for (; e < ee; e += 2) {
        const int c = col[e];
        const float4 v = *(const float4*)(h + (size_t)c * DD + f);
        a0.x += v.x; a0.y += v.y; a0.z += v.z; a0.w += v.w;
    }
    float4 s;
    s.x = (a0.x + a1.x) + (a2.x + a3.x);
    s.y = (a0.y + a1.y) + (a2.y + a3.y);
    s.z = (a0.z + a1.z) + (a2.z + a3.z);
    s.w = (a0.w + a1.w) + (a2.w + a3.w);
    s.x += __shfl_xor(s.x, 32, 64);
    s.y += __shfl_xor(s.y, 32, 64);
    s.z += __shfl_xor(s.z, 32, 64);
    s.w += __shfl_xor(s.w, 32, 64);
    if (half == 0)
        *(float4*)(agg + (size_t)row * DD + f) = s;
}

// ---------------- fused layer GEMMs: h2 = relu(agg@Wg+bg) + relu(h@Wr+br), + BN sums --------
// KEY FIX vs R3: wave id forced into an SGPR via readfirstlane so c0 (column
// offset) is compiler-provably wave-uniform -> weight/bias loads become s_load
// through the constant cache instead of per-lane global_load_dword.
__global__ __launch_bounds__(256, 2) void k_layer(const float* __restrict__ hin,
                                                  const float* __restrict__ aggin,
                                                  const float* __restrict__ Wg,
                                                  const float* __restrict__ bg,
                                                  const float* __restrict__ Wr,
                                                  const float* __restrict__ br,
                                                  float* __restrict__ h2out,
                                                  float* sums) {
    __shared__ float sA[64 * 129];
    __shared__ float sH[64 * 129];
    const int tid = threadIdx.x;
    const int r0 = blockIdx.x * 64;
    {
        const float4* A4 = (const float4*)(aggin + (size_t)r0 * DD);
        const float4* H4 = (const float4*)(hin + (size_t)r0 * DD);
        #pragma unroll
        for (int i = 0; i < 8; ++i) {
            const int idx4 = tid + i * 256;
            const int base = idx4 * 4;
            const int r = base >> 7;
            const int k = base & 127;
            const float4 a = A4[idx4];
            const float4 hh = H4[idx4];
            float* pa = &sA[r * 129 + k];
            pa[0] = a.x; pa[1] = a.y; pa[2] = a.z; pa[3] = a.w;
            float* ph = &sH[r * 129 + k];
            ph[0] = hh.x; ph[1] = hh.y; ph[2] = hh.z; ph[3] = hh.w;
        }
    }
    __syncthreads();
    const int wvS = __builtin_amdgcn_readfirstlane(tid >> 6);  // SGPR wave id
    const int lane = tid & 63;
    const int row = r0 + lane;
    const float* sArow = &sA[lane * 129];
    const float* sHrow = &sH[lane * 129];

    for (int ct = 0; ct < 2; ++ct) {
        const int c0 = wvS * 32 + ct * 16;   // scalar -> s_load weight path
        float accg[16], accr[16];
        #pragma unroll
        for (int j = 0; j < 16; ++j) { accg[j] = 0.0f; accr[j] = 0.0f; }
        #pragma unroll 4
        for (int k = 0; k < DD; ++k) {
            const float a = sArow[k];
            const float hh = sHrow[k];
            const float* wgk = Wg + k * DD + c0;
            const float* wrk = Wr + k * DD + c0;
            #pragma unroll
            for (int j = 0; j < 16; ++j) {
                accg[j] = fmaf(a, wgk[j], accg[j]);
                accr[j] = fmaf(hh, wrk[j], accr[j]);
            }
        }
        float* outrow = h2out + (size_t)row * DD + c0;
        #pragma unroll
        for (int j = 0; j < 16; ++j) {
            float g = accg[j] + bg[c0 + j];
            g = fmaxf(g, 0.0f);
            float rr = accr[j] + br[c0 + j];
            rr = fmaxf(rr, 0.0f);
            const float v = g + rr;
            outrow[j] = v;
            float s = v, s2 = v * v;
            #pragma unroll
            for (int off = 32; off > 0; off >>= 1) {
                s += __shfl_xor(s, off, 64);
                s2 += __shfl_xor(s2, off, 64);
            }
            accg[j] = s;
            accr[j] = s2;
        }
        if (lane == 0) {
            #pragma unroll
            for (int j = 0; j < 16; ++j) {
                atomicAdd(&sums[c0 + j], accg[j]);
                atomicAdd(&sums[DD + c0 + j], accr[j]);
            }
        }
    }
}

// ---------------- BatchNorm normalize ----------------
__global__ __launch_bounds__(256) void k_bn(const float* __restrict__ h2,
                                            const float* __restrict__ sums,
                                            const float* __restrict__ gamma,
                                            const float* __restrict__ beta,
                                            float* __restrict__ out) {
    const int t = blockIdx.x * 256 + threadIdx.x;  // NN*32 threads
    const size_t base = (size_t)t * 4;
    const int c = (int)(base & 127);
    const float4 v = *(const float4*)(h2 + base);
    const float4 s = *(const float4*)(sums + c);
    const float4 s2 = *(const float4*)(sums + DD + c);
    const float4 g = *(const float4*)(gamma + c);
    const float4 b = *(const float4*)(beta + c);
    const float invN = 1.0f / (float)NN;
    float4 o;
    {
        float mu = s.x * invN; float var = s2.x * invN - mu * mu;
        o.x = (v.x - mu) * (g.x * rsqrtf(var + EPS)) + b.x;
    }
    {
        float mu = s.y * invN; float var = s2.y * invN - mu * mu;
        o.y = (v.y - mu) * (g.y * rsqrtf(var + EPS)) + b.y;
    }
    {
        float mu = s.z * invN; float var = s2.z * invN - mu * mu;
        o.z = (v.z - mu) * (g.z * rsqrtf(var + EPS)) + b.z;
    }
    {
        float mu = s.w * invN; float var = s2.w * invN - mu * mu;
        o.w = (v.w - mu) * (g.w * rsqrtf(var + EPS)) + b.w;
    }
    *(float4*)(out + base) = o;
}

extern "C" void kernel_launch(void* const* d_in, const int* in_sizes, int n_in,
                              void* d_out, int out_size, void* d_ws, size_t ws_size,
                              hipStream_t stream) {
    const float* X     = (const float*)d_in[0];
    const int*   src   = (const int*)d_in[1];
    const int*   dst   = (const int*)d_in[2];
    const float* Wi    = (const float*)d_in[3];
    const float* Wg    = (const float*)d_in[4];
    const float* bg    = (const float*)d_in[5];
    const float* Wr    = (const float*)d_in[6];
    const float* br    = (const float*)d_in[7];
    const float* gamma = (const float*)d_in[8];
    const float* beta  = (const float*)d_in[9];
    float* out = (float*)d_out;

    float* h    = (float*)d_ws;                       // [NN*DD]
    float* agg  = h + (size_t)NN * DD;                // [NN*DD]
    float* sums = agg + (size_t)NN * DD;              // [NL*2*DD]
    int* rowptr = (int*)(sums + NL * 2 * DD);         // [NN+1]
    int* col    = rowptr + NN + 1;                    // [NE]
    // CSR-build scratch aliased into agg (dead once k_fill completes)
    int* cnt    = (int*)agg;                          // [NN]
    int* offs   = cnt + NN;                           // [NN]
    float* h2   = out;                                // reuse d_out as h2 scratch

    hipMemsetAsync(sums, 0, NL * 2 * DD * sizeof(float), stream);
    hipMemsetAsync(cnt, 0, NN * sizeof(int), stream);

    k_init<<<NN / 64, 64, 0, stream>>>(X, Wi, h);
    k_hist<<<NE / 256, 256, 0, stream>>>(dst, cnt);
    k_scan<<<1, 1024, 0, stream>>>(cnt, rowptr, offs);
    k_fill<<<NE / 256, 256, 0, stream>>>(src, dst, offs, col);

    for (int l = 0; l < NL; ++l) {
        k_gather<<<NN / 4, 256, 0, stream>>>(h, rowptr, col, agg);
        k_layer<<<NN / 64, 256, 0, stream>>>(h, agg,
                                             Wg + l * DD * DD, bg + l * DD,
                                             Wr + l * DD * DD, br + l * DD,
                                             h2, sums + l * 2 * DD);
        float* outp = (l == NL - 1) ? out : h;
        k_bn<<<(NN * 32) / 256, 256, 0, stream>>>(h2, sums + l * 2 * DD,
                                                  gamma + l * DD, beta + l * DD, outp);
    }
}

// Round 5
// 813.907 us; speedup vs baseline: 6.0578x; 2.7098x over previous
//
#include <hip/hip_runtime.h>

#define NN 74240      // nodes
#define NE 593920     // edges
#define DIN 75
#define DD 128
#define NL 3
#define EPS 1e-5f

// ---------------- init GEMM: h = X @ W_init  ([NN,75] @ [75,128]) ----------------
__global__ __launch_bounds__(64) void k_init(const float* __restrict__ X,
                                             const float* __restrict__ W,
                                             float* __restrict__ h) {
    __shared__ float sX[64 * 77];
    const int r0 = blockIdx.x * 64;
    const int lane = threadIdx.x;
    const float* Xb = X + (size_t)r0 * DIN;
    for (int e = lane; e < 64 * DIN; e += 64) {
        int r = e / DIN;
        int k = e - r * DIN;
        sX[r * 77 + k] = Xb[e];
    }
    __syncthreads();
    float* hrow = h + (size_t)(r0 + lane) * DD;
    const float* xr = &sX[lane * 77];
    for (int ct = 0; ct < 8; ++ct) {
        const int c0 = ct * 16;
        float acc[16];
        #pragma unroll
        for (int j = 0; j < 16; ++j) acc[j] = 0.0f;
        #pragma unroll 5
        for (int k = 0; k < DIN; ++k) {
            const float a = xr[k];
            const float* wk = W + k * DD + c0;
            #pragma unroll
            for (int j = 0; j < 16; ++j)
                acc[j] = fmaf(a, wk[j], acc[j]);
        }
        #pragma unroll
        for (int j = 0; j < 16; ++j) hrow[c0 + j] = acc[j];
    }
}

// ---------------- CSR build: histogram -> scan -> fill ----------------
__global__ __launch_bounds__(256) void k_hist(const int* __restrict__ dst, int* cnt) {
    const int e = blockIdx.x * 256 + threadIdx.x;   // grid == NE
    atomicAdd(&cnt[dst[e]], 1);
}

__global__ __launch_bounds__(1024) void k_scan(const int* __restrict__ cnt,
                                               int* __restrict__ rowptr,
                                               int* __restrict__ offs) {
    __shared__ int sdata[1024];
    const int t = threadIdx.x;
    const int i0 = t * 73;
    const int i1 = (i0 + 73 < NN) ? (i0 + 73) : NN;
    int p = 0;
    for (int i = i0; i < i1; ++i) p += cnt[i];
    sdata[t] = p;
    __syncthreads();
    for (int off = 1; off < 1024; off <<= 1) {
        int v = (t >= off) ? sdata[t - off] : 0;
        __syncthreads();
        sdata[t] += v;
        __syncthreads();
    }
    int run = (t > 0) ? sdata[t - 1] : 0;
    for (int i = i0; i < i1; ++i) {
        rowptr[i] = run;
        offs[i] = run;
        run += cnt[i];
    }
    if (t == 0) rowptr[NN] = NE;
}

__global__ __launch_bounds__(256) void k_fill(const int* __restrict__ src,
                                              const int* __restrict__ dst,
                                              int* offs, int* __restrict__ col) {
    const int e = blockIdx.x * 256 + threadIdx.x;   // grid == NE
    const int pos = atomicAdd(&offs[dst[e]], 1);
    col[pos] = src[e];
}

// ---------------- gather: agg[row] = sum_{e in row} h[col[e]] ----------------
__global__ __launch_bounds__(256) void k_gather(const float* __restrict__ h,
                                                const int* __restrict__ rowptr,
                                                const int* __restrict__ col,
                                                float* __restrict__ agg) {
    const int wave = threadIdx.x >> 6;
    const int lane = threadIdx.x & 63;
    const int row = blockIdx.x * 4 + wave;   // grid = NN/4
    const int eb = rowptr[row];
    const int ee = rowptr[row + 1];
    const int half = lane >> 5;
    const int f = (lane & 31) * 4;
    float4 a0 = {0.f,0.f,0.f,0.f}, a1 = {0.f,0.f,0.f,0.f};
    float4 a2 = {0.f,0.f,0.f,0.f}, a3 = {0.f,0.f,0.f,0.f};
    int e = eb + half;
    for (; e + 6 < ee; e += 8) {
        const int c0 = col[e], c1 = col[e + 2], c2 = col[e + 4], c3 = col[e + 6];
        const float4 v0 = *(const float4*)(h + (size_t)c0 * DD + f);
        const float4 v1 = *(const float4*)(h + (size_t)c1 * DD + f);
        const float4 v2 = *(const float4*)(h + (size_t)c2 * DD + f);
        const float4 v3 = *(const float4*)(h + (size_t)c3 * DD + f);
        a0.x += v0.x; a0.y += v0.y; a0.z += v0.z; a0.w += v0.w;
        a1.x += v1.x; a1.y += v1.y; a1.z += v1.z; a1.w += v1.w;
        a2.x += v2.x; a2.y += v2.y; a2.z += v2.z; a2.w += v2.w;
        a3.x += v3.x; a3.y += v3.y; a3.z += v3.z; a3.w += v3.w;
    }
    for (; e < ee; e += 2) {
        const int c = col[e];
        const float4 v = *(const float4*)(h + (size_t)c * DD + f);
        a0.x += v.x; a0.y += v.y; a0.z += v.z; a0.w += v.w;
    }
    float4 s;
    s.x = (a0.x + a1.x) + (a2.x + a3.x);
    s.y = (a0.y + a1.y) + (a2.y + a3.y);
    s.z = (a0.z + a1.z) + (a2.z + a3.z);
    s.w = (a0.w + a1.w) + (a2.w + a3.w);
    s.x += __shfl_xor(s.x, 32, 64);
    s.y += __shfl_xor(s.y, 32, 64);
    s.z += __shfl_xor(s.z, 32, 64);
    s.w += __shfl_xor(s.w, 32, 64);
    if (half == 0)
        *(float4*)(agg + (size_t)row * DD + f) = s;
}

// ---------------- fused layer GEMMs (register-tiled) ----------------
// Block: 32 rows x 128 cols. 256 threads; thread (tr=tid>>5, tc=tid&31) computes
// rows tr*4..+4, cols tc*4..+4 for BOTH GEMMs (4x4x2 = 32 fp32 accs).
// A/H staged once in LDS [32][132] (pad 132: b128 row-reads broadcast, conflict-free).
// Weights streamed through LDS in K-chunks of 32 ([32][128] x2 = 32 KB).
// Per 4-k group: 16 ds_read_b128 feed 128 FMAs (mem:FMA = 1:8) — vs R4's 1:1
// per-lane global weight loads that saturated the VMEM pipe at 10 cyc/instr.
#define LA 132
__global__ __launch_bounds__(256, 2) void k_layer(const float* __restrict__ hin,
                                                  const float* __restrict__ aggin,
                                                  const float* __restrict__ Wg,
                                                  const float* __restrict__ bg,
                                                  const float* __restrict__ Wr,
                                                  const float* __restrict__ br,
                                                  float* __restrict__ h2out,
                                                  float* sums) {
    __shared__ float sA[32 * LA];
    __shared__ float sH[32 * LA];
    __shared__ float sWg[32 * 128];
    __shared__ float sWr[32 * 128];
    __shared__ float sSum[256];
    const int tid = threadIdx.x;
    const int r0 = blockIdx.x * 32;
    const int tr = tid >> 5;          // 0..7
    const int tc = tid & 31;          // 0..31
    const int c0 = tc * 4;

    // stage A (agg) and H (residual input): 1024 float4 each
    {
        const float4* A4 = (const float4*)(aggin + (size_t)r0 * DD);
        const float4* H4 = (const float4*)(hin + (size_t)r0 * DD);
        #pragma unroll
        for (int it = 0; it < 4; ++it) {
            const int idx4 = tid + it * 256;
            const int r = idx4 >> 5;
            const int kc = (idx4 & 31) * 4;
            *(float4*)&sA[r * LA + kc] = A4[idx4];
            *(float4*)&sH[r * LA + kc] = H4[idx4];
        }
        sSum[tid] = 0.0f;
    }

    float4 accg[4], accr[4];
    #pragma unroll
    for (int i = 0; i < 4; ++i) {
        accg[i] = make_float4(0.f, 0.f, 0.f, 0.f);
        accr[i] = make_float4(0.f, 0.f, 0.f, 0.f);
    }

    for (int kb = 0; kb < 4; ++kb) {
        __syncthreads();
        // stage weight K-chunk: rows kb*32..+32, all 128 cols, both matrices
        {
            const float4* G4 = (const float4*)(Wg + kb * 32 * DD);
            const float4* R4 = (const float4*)(Wr + kb * 32 * DD);
            #pragma unroll
            for (int it = 0; it < 4; ++it) {
                const int idx4 = tid + it * 256;
                ((float4*)sWg)[idx4] = G4[idx4];
                ((float4*)sWr)[idx4] = R4[idx4];
            }
        }
        __syncthreads();
        const int kbase = kb * 32;
        for (int k4 = 0; k4 < 32; k4 += 4) {
            float4 wg[4], wr[4];
            #pragma unroll
            for (int kk = 0; kk < 4; ++kk) {
                wg[kk] = *(const float4*)&sWg[(k4 + kk) * 128 + c0];
                wr[kk] = *(const float4*)&sWr[(k4 + kk) * 128 + c0];
            }
            #pragma unroll
            for (int i = 0; i < 4; ++i) {
                const int r = tr * 4 + i;
                const float4 av = *(const float4*)&sA[r * LA + kbase + k4];
                const float4 hv = *(const float4*)&sH[r * LA + kbase + k4];
                accg[i].x = fmaf(av.x, wg[0].x, accg[i].x); accg[i].y = fmaf(av.x, wg[0].y, accg[i].y);
                accg[i].z = fmaf(av.x, wg[0].z, accg[i].z); accg[i].w = fmaf(av.x, wg[0].w, accg[i].w);
                accg[i].x = fmaf(av.y, wg[1].x, accg[i].x); accg[i].y = fmaf(av.y, wg[1].y, accg[i].y);
                accg[i].z = fmaf(av.y, wg[1].z, accg[i].z); accg[i].w = fmaf(av.y, wg[1].w, accg[i].w);
                accg[i].x = fmaf(av.z, wg[2].x, accg[i].x); accg[i].y = fmaf(av.z, wg[2].y, accg[i].y);
                accg[i].z = fmaf(av.z, wg[2].z, accg[i].z); accg[i].w = fmaf(av.z, wg[2].w, accg[i].w);
                accg[i].x = fmaf(av.w, wg[3].x, accg[i].x); accg[i].y = fmaf(av.w, wg[3].y, accg[i].y);
                accg[i].z = fmaf(av.w, wg[3].z, accg[i].z); accg[i].w = fmaf(av.w, wg[3].w, accg[i].w);
                accr[i].x = fmaf(hv.x, wr[0].x, accr[i].x); accr[i].y = fmaf(hv.x, wr[0].y, accr[i].y);
                accr[i].z = fmaf(hv.x, wr[0].z, accr[i].z); accr[i].w = fmaf(hv.x, wr[0].w, accr[i].w);
                accr[i].x = fmaf(hv.y, wr[1].x, accr[i].x); accr[i].y = fmaf(hv.y, wr[1].y, accr[i].y);
                accr[i].z = fmaf(hv.y, wr[1].z, accr[i].z); accr[i].w = fmaf(hv.y, wr[1].w, accr[i].w);
                accr[i].x = fmaf(hv.z, wr[2].x, accr[i].x); accr[i].y = fmaf(hv.z, wr[2].y, accr[i].y);
                accr[i].z = fmaf(hv.z, wr[2].z, accr[i].z); accr[i].w = fmaf(hv.z, wr[2].w, accr[i].w);
                accr[i].x = fmaf(hv.w, wr[3].x, accr[i].x); accr[i].y = fmaf(hv.w, wr[3].y, accr[i].y);
                accr[i].z = fmaf(hv.w, wr[3].z, accr[i].z); accr[i].w = fmaf(hv.w, wr[3].w, accr[i].w);
            }
        }
    }

    // epilogue: bias + relu + add, store h2, BN partial sums
    const float4 bgv = *(const float4*)(bg + c0);
    const float4 brv = *(const float4*)(br + c0);
    float4 s = make_float4(0.f, 0.f, 0.f, 0.f);
    float4 s2 = make_float4(0.f, 0.f, 0.f, 0.f);
    #pragma unroll
    for (int i = 0; i < 4; ++i) {
        const int r = tr * 4 + i;
        float4 v;
        v.x = fmaxf(accg[i].x + bgv.x, 0.f) + fmaxf(accr[i].x + brv.x, 0.f);
        v.y = fmaxf(accg[i].y + bgv.y, 0.f) + fmaxf(accr[i].y + brv.y, 0.f);
        v.z = fmaxf(accg[i].z + bgv.z, 0.f) + fmaxf(accr[i].z + brv.z, 0.f);
        v.w = fmaxf(accg[i].w + bgv.w, 0.f) + fmaxf(accr[i].w + brv.w, 0.f);
        *(float4*)(h2out + (size_t)(r0 + r) * DD + c0) = v;
        s.x += v.x; s.y += v.y; s.z += v.z; s.w += v.w;
        s2.x += v.x * v.x; s2.y += v.y * v.y; s2.z += v.z * v.z; s2.w += v.w * v.w;
    }
    // combine tr pairs within wave (lane^32 = other tr, same tc)
    s.x += __shfl_xor(s.x, 32, 64);   s.y += __shfl_xor(s.y, 32, 64);
    s.z += __shfl_xor(s.z, 32, 64);   s.w += __shfl_xor(s.w, 32, 64);
    s2.x += __shfl_xor(s2.x, 32, 64); s2.y += __shfl_xor(s2.y, 32, 64);
    s2.z += __shfl_xor(s2.z, 32, 64); s2.w += __shfl_xor(s2.w, 32, 64);
    if ((tid & 63) < 32) {
        atomicAdd(&sSum[c0 + 0], s.x);  atomicAdd(&sSum[c0 + 1], s.y);
        atomicAdd(&sSum[c0 + 2], s.z);  atomicAdd(&sSum[c0 + 3], s.w);
        atomicAdd(&sSum[128 + c0 + 0], s2.x); atomicAdd(&sSum[128 + c0 + 1], s2.y);
        atomicAdd(&sSum[128 + c0 + 2], s2.z); atomicAdd(&sSum[128 + c0 + 3], s2.w);
    }
    __syncthreads();
    atomicAdd(&sums[tid], sSum[tid]);   // sums layout: [s(128) | s2(128)]
}

// ---------------- BatchNorm normalize ----------------
__global__ __launch_bounds__(256) void k_bn(const float* __restrict__ h2,
                                            const float* __restrict__ sums,
                                            const float* __restrict__ gamma,
                                            const float* __restrict__ beta,
                                            float* __restrict__ out) {
    const int t = blockIdx.x * 256 + threadIdx.x;  // NN*32 threads
    const size_t base = (size_t)t * 4;
    const int c = (int)(base & 127);
    const float4 v = *(const float4*)(h2 + base);
    const float4 s = *(const float4*)(sums + c);
    const float4 s2 = *(const float4*)(sums + DD + c);
    const float4 g = *(const float4*)(gamma + c);
    const float4 b = *(const float4*)(beta + c);
    const float invN = 1.0f / (float)NN;
    float4 o;
    {
        float mu = s.x * invN; float var = s2.x * invN - mu * mu;
        o.x = (v.x - mu) * (g.x * rsqrtf(var + EPS)) + b.x;
    }
    {
        float mu = s.y * invN; float var = s2.y * invN - mu * mu;
        o.y = (v.y - mu) * (g.y * rsqrtf(var + EPS)) + b.y;
    }
    {
        float mu = s.z * invN; float var = s2.z * invN - mu * mu;
        o.z = (v.z - mu) * (g.z * rsqrtf(var + EPS)) + b.z;
    }
    {
        float mu = s.w * invN; float var = s2.w * invN - mu * mu;
        o.w = (v.w - mu) * (g.w * rsqrtf(var + EPS)) + b.w;
    }
    *(float4*)(out + base) = o;
}

extern "C" void kernel_launch(void* const* d_in, const int* in_sizes, int n_in,
                              void* d_out, int out_size, void* d_ws, size_t ws_size,
                              hipStream_t stream) {
    const float* X     = (const float*)d_in[0];
    const int*   src   = (const int*)d_in[1];
    const int*   dst   = (const int*)d_in[2];
    const float* Wi    = (const float*)d_in[3];
    const float* Wg    = (const float*)d_in[4];
    const float* bg    = (const float*)d_in[5];
    const float* Wr    = (const float*)d_in[6];
    const float* br    = (const float*)d_in[7];
    const float* gamma = (const float*)d_in[8];
    const float* beta  = (const float*)d_in[9];
    float* out = (float*)d_out;

    float* h    = (float*)d_ws;                       // [NN*DD]
    float* agg  = h + (size_t)NN * DD;                // [NN*DD]
    float* sums = agg + (size_t)NN * DD;              // [NL*2*DD]
    int* rowptr = (int*)(sums + NL * 2 * DD);         // [NN+1]
    int* col    = rowptr + NN + 1;                    // [NE]
    // CSR-build scratch aliased into agg (dead once k_fill completes)
    int* cnt    = (int*)agg;                          // [NN]
    int* offs   = cnt + NN;                           // [NN]
    float* h2   = out;                                // reuse d_out as h2 scratch

    hipMemsetAsync(sums, 0, NL * 2 * DD * sizeof(float), stream);
    hipMemsetAsync(cnt, 0, NN * sizeof(int), stream);

    k_init<<<NN / 64, 64, 0, stream>>>(X, Wi, h);
    k_hist<<<NE / 256, 256, 0, stream>>>(dst, cnt);
    k_scan<<<1, 1024, 0, stream>>>(cnt, rowptr, offs);
    k_fill<<<NE / 256, 256, 0, stream>>>(src, dst, offs, col);

    for (int l = 0; l < NL; ++l) {
        k_gather<<<NN / 4, 256, 0, stream>>>(h, rowptr, col, agg);
        k_layer<<<NN / 32, 256, 0, stream>>>(h, agg,
                                             Wg + l * DD * DD, bg + l * DD,
                                             Wr + l * DD * DD, br + l * DD,
                                             h2, sums + l * 2 * DD);
        float* outp = (l == NL - 1) ? out : h;
        k_bn<<<(NN * 32) / 256, 256, 0, stream>>>(h2, sums + l * 2 * DD,
                                                  gamma + l * DD, beta + l * DD, outp);
    }
}

// Round 6
// 665.992 us; speedup vs baseline: 7.4032x; 1.2221x over previous
//
#include <hip/hip_runtime.h>

#define NN 74240      // nodes
#define NE 593920     // edges
#define DIN 75
#define DD 128
#define NL 3
#define EPS 1e-5f
#define NB 290        // scan blocks: 290*256 == NN

// ---------------- init GEMM: h = X @ W_init  ([NN,75] @ [75,128]) ----------------
__global__ __launch_bounds__(64) void k_init(const float* __restrict__ X,
                                             const float* __restrict__ W,
                                             float* __restrict__ h) {
    __shared__ float sX[64 * 77];
    const int r0 = blockIdx.x * 64;
    const int lane = threadIdx.x;
    const float* Xb = X + (size_t)r0 * DIN;
    for (int e = lane; e < 64 * DIN; e += 64) {
        int r = e / DIN;
        int k = e - r * DIN;
        sX[r * 77 + k] = Xb[e];
    }
    __syncthreads();
    float* hrow = h + (size_t)(r0 + lane) * DD;
    const float* xr = &sX[lane * 77];
    for (int ct = 0; ct < 8; ++ct) {
        const int c0 = ct * 16;
        float acc[16];
        #pragma unroll
        for (int j = 0; j < 16; ++j) acc[j] = 0.0f;
        #pragma unroll 5
        for (int k = 0; k < DIN; ++k) {
            const float a = xr[k];
            const float* wk = W + k * DD + c0;
            #pragma unroll
            for (int j = 0; j < 16; ++j)
                acc[j] = fmaf(a, wk[j], acc[j]);
        }
        #pragma unroll
        for (int j = 0; j < 16; ++j) hrow[c0 + j] = acc[j];
    }
}

// ---------------- CSR build: histogram -> 3-phase scan -> fill ----------------
__global__ __launch_bounds__(256) void k_hist(const int* __restrict__ dst, int* cnt) {
    const int e = blockIdx.x * 256 + threadIdx.x;   // grid == NE
    atomicAdd(&cnt[dst[e]], 1);
}

// phase 1: per-block (256-node) sums
__global__ __launch_bounds__(256) void k_scan1(const int* __restrict__ cnt,
                                               int* __restrict__ bsum) {
    const int tid = threadIdx.x;
    int v = cnt[blockIdx.x * 256 + tid];
    #pragma unroll
    for (int off = 1; off < 64; off <<= 1) v += __shfl_xor(v, off, 64);
    __shared__ int ws[4];
    if ((tid & 63) == 0) ws[tid >> 6] = v;
    __syncthreads();
    if (tid == 0) bsum[blockIdx.x] = ws[0] + ws[1] + ws[2] + ws[3];
}

// phase 2: exclusive scan of the NB block sums (single block)
__global__ __launch_bounds__(512) void k_scan2(const int* __restrict__ bsum,
                                               int* __restrict__ boff) {
    __shared__ int s[512];
    const int t = threadIdx.x;
    const int v = (t < NB) ? bsum[t] : 0;
    s[t] = v;
    __syncthreads();
    for (int off = 1; off < 512; off <<= 1) {
        const int u = (t >= off) ? s[t - off] : 0;
        __syncthreads();
        s[t] += u;
        __syncthreads();
    }
    if (t < NB) boff[t] = s[t] - v;   // exclusive
}

// phase 3: in-block exclusive scan + block offset -> rowptr/offs
__global__ __launch_bounds__(256) void k_scan3(const int* __restrict__ cnt,
                                               const int* __restrict__ boff,
                                               int* __restrict__ rowptr,
                                               int* __restrict__ offs) {
    const int tid = threadIdx.x;
    const int t = blockIdx.x * 256 + tid;
    const int lane = tid & 63;
    const int v = cnt[t];
    int inc = v;
    #pragma unroll
    for (int off = 1; off < 64; off <<= 1) {
        const int u = __shfl_up(inc, off, 64);
        if (lane >= off) inc += u;
    }
    __shared__ int ws[4];
    if (lane == 63) ws[tid >> 6] = inc;
    __syncthreads();
    const int w = tid >> 6;
    int waveoff = 0;
    for (int i = 0; i < 4; ++i) waveoff += (i < w) ? ws[i] : 0;
    const int excl = boff[blockIdx.x] + waveoff + inc - v;
    rowptr[t] = excl;
    offs[t] = excl;
    if (blockIdx.x == NB - 1 && tid == 255) rowptr[NN] = NE;
}

__global__ __launch_bounds__(256) void k_fill(const int* __restrict__ src,
                                              const int* __restrict__ dst,
                                              int* offs, int* __restrict__ col) {
    const int e = blockIdx.x * 256 + threadIdx.x;   // grid == NE
    const int pos = atomicAdd(&offs[dst[e]], 1);
    col[pos] = src[e];
}

// ---------------- gather: agg[row] = sum_{e in row} h[col[e]] ----------------
__global__ __launch_bounds__(256) void k_gather(const float* __restrict__ h,
                                                const int* __restrict__ rowptr,
                                                const int* __restrict__ col,
                                                float* __restrict__ agg) {
    const int wave = threadIdx.x >> 6;
    const int lane = threadIdx.x & 63;
    const int row = blockIdx.x * 4 + wave;   // grid = NN/4
    const int eb = rowptr[row];
    const int ee = rowptr[row + 1];
    const int half = lane >> 5;
    const int f = (lane & 31) * 4;
    float4 a0 = {0.f,0.f,0.f,0.f}, a1 = {0.f,0.f,0.f,0.f};
    float4 a2 = {0.f,0.f,0.f,0.f}, a3 = {0.f,0.f,0.f,0.f};
    int e = eb + half;
    for (; e + 6 < ee; e += 8) {
        const int c0 = col[e], c1 = col[e + 2], c2 = col[e + 4], c3 = col[e + 6];
        const float4 v0 = *(const float4*)(h + (size_t)c0 * DD + f);
        const float4 v1 = *(const float4*)(h + (size_t)c1 * DD + f);
        const float4 v2 = *(const float4*)(h + (size_t)c2 * DD + f);
        const float4 v3 = *(const float4*)(h + (size_t)c3 * DD + f);
        a0.x += v0.x; a0.y += v0.y; a0.z += v0.z; a0.w += v0.w;
        a1.x += v1.x; a1.y += v1.y; a1.z += v1.z; a1.w += v1.w;
        a2.x += v2.x; a2.y += v2.y; a2.z += v2.z; a2.w += v2.w;
        a3.x += v3.x; a3.y += v3.y; a3.z += v3.z; a3.w += v3.w;
    }
    for (; e < ee; e += 2) {
        const int c = col[e];
        const float4 v = *(const float4*)(h + (size_t)c * DD + f);
        a0.x += v.x; a0.y += v.y; a0.z += v.z; a0.w += v.w;
    }
    float4 s;
    s.x = (a0.x + a1.x) + (a2.x + a3.x);
    s.y = (a0.y + a1.y) + (a2.y + a3.y);
    s.z = (a0.z + a1.z) + (a2.z + a3.z);
    s.w = (a0.w + a1.w) + (a2.w + a3.w);
    s.x += __shfl_xor(s.x, 32, 64);
    s.y += __shfl_xor(s.y, 32, 64);
    s.z += __shfl_xor(s.z, 32, 64);
    s.w += __shfl_xor(s.w, 32, 64);
    if (half == 0)
        *(float4*)(agg + (size_t)row * DD + f) = s;
}

// ---------------- fused layer GEMMs (register-tiled) ----------------
#define LA 132
__global__ __launch_bounds__(256, 2) void k_layer(const float* __restrict__ hin,
                                                  const float* __restrict__ aggin,
                                                  const float* __restrict__ Wg,
                                                  const float* __restrict__ bg,
                                                  const float* __restrict__ Wr,
                                                  const float* __restrict__ br,
                                                  float* __restrict__ h2out,
                                                  float* sums) {
    __shared__ float sA[32 * LA];
    __shared__ float sH[32 * LA];
    __shared__ float sWg[32 * 128];
    __shared__ float sWr[32 * 128];
    __shared__ float sSum[256];
    const int tid = threadIdx.x;
    const int r0 = blockIdx.x * 32;
    const int tr = tid >> 5;          // 0..7
    const int tc = tid & 31;          // 0..31
    const int c0 = tc * 4;

    {
        const float4* A4 = (const float4*)(aggin + (size_t)r0 * DD);
        const float4* H4 = (const float4*)(hin + (size_t)r0 * DD);
        #pragma unroll
        for (int it = 0; it < 4; ++it) {
            const int idx4 = tid + it * 256;
            const int r = idx4 >> 5;
            const int kc = (idx4 & 31) * 4;
            *(float4*)&sA[r * LA + kc] = A4[idx4];
            *(float4*)&sH[r * LA + kc] = H4[idx4];
        }
        sSum[tid] = 0.0f;
    }

    float4 accg[4], accr[4];
    #pragma unroll
    for (int i = 0; i < 4; ++i) {
        accg[i] = make_float4(0.f, 0.f, 0.f, 0.f);
        accr[i] = make_float4(0.f, 0.f, 0.f, 0.f);
    }

    for (int kb = 0; kb < 4; ++kb) {
        __syncthreads();
        {
            const float4* G4 = (const float4*)(Wg + kb * 32 * DD);
            const float4* R4 = (const float4*)(Wr + kb * 32 * DD);
            #pragma unroll
            for (int it = 0; it < 4; ++it) {
                const int idx4 = tid + it * 256;
                ((float4*)sWg)[idx4] = G4[idx4];
                ((float4*)sWr)[idx4] = R4[idx4];
            }
        }
        __syncthreads();
        const int kbase = kb * 32;
        for (int k4 = 0; k4 < 32; k4 += 4) {
            float4 wg[4], wr[4];
            #pragma unroll
            for (int kk = 0; kk < 4; ++kk) {
                wg[kk] = *(const float4*)&sWg[(k4 + kk) * 128 + c0];
                wr[kk] = *(const float4*)&sWr[(k4 + kk) * 128 + c0];
            }
            #pragma unroll
            for (int i = 0; i < 4; ++i) {
                const int r = tr * 4 + i;
                const float4 av = *(const float4*)&sA[r * LA + kbase + k4];
                const float4 hv = *(const float4*)&sH[r * LA + kbase + k4];
                accg[i].x = fmaf(av.x, wg[0].x, accg[i].x); accg[i].y = fmaf(av.x, wg[0].y, accg[i].y);
                accg[i].z = fmaf(av.x, wg[0].z, accg[i].z); accg[i].w = fmaf(av.x, wg[0].w, accg[i].w);
                accg[i].x = fmaf(av.y, wg[1].x, accg[i].x); accg[i].y = fmaf(av.y, wg[1].y, accg[i].y);
                accg[i].z = fmaf(av.y, wg[1].z, accg[i].z); accg[i].w = fmaf(av.y, wg[1].w, accg[i].w);
                accg[i].x = fmaf(av.z, wg[2].x, accg[i].x); accg[i].y = fmaf(av.z, wg[2].y, accg[i].y);
                accg[i].z = fmaf(av.z, wg[2].z, accg[i].z); accg[i].w = fmaf(av.z, wg[2].w, accg[i].w);
                accg[i].x = fmaf(av.w, wg[3].x, accg[i].x); accg[i].y = fmaf(av.w, wg[3].y, accg[i].y);
                accg[i].z = fmaf(av.w, wg[3].z, accg[i].z); accg[i].w = fmaf(av.w, wg[3].w, accg[i].w);
                accr[i].x = fmaf(hv.x, wr[0].x, accr[i].x); accr[i].y = fmaf(hv.x, wr[0].y, accr[i].y);
                accr[i].z = fmaf(hv.x, wr[0].z, accr[i].z); accr[i].w = fmaf(hv.x, wr[0].w, accr[i].w);
                accr[i].x = fmaf(hv.y, wr[1].x, accr[i].x); accr[i].y = fmaf(hv.y, wr[1].y, accr[i].y);
                accr[i].z = fmaf(hv.y, wr[1].z, accr[i].z); accr[i].w = fmaf(hv.y, wr[1].w, accr[i].w);
                accr[i].x = fmaf(hv.z, wr[2].x, accr[i].x); accr[i].y = fmaf(hv.z, wr[2].y, accr[i].y);
                accr[i].z = fmaf(hv.z, wr[2].z, accr[i].z); accr[i].w = fmaf(hv.z, wr[2].w, accr[i].w);
                accr[i].x = fmaf(hv.w, wr[3].x, accr[i].x); accr[i].y = fmaf(hv.w, wr[3].y, accr[i].y);
                accr[i].z = fmaf(hv.w, wr[3].z, accr[i].z); accr[i].w = fmaf(hv.w, wr[3].w, accr[i].w);
            }
        }
    }

    const float4 bgv = *(const float4*)(bg + c0);
    const float4 brv = *(const float4*)(br + c0);
    float4 s = make_float4(0.f, 0.f, 0.f, 0.f);
    float4 s2 = make_float4(0.f, 0.f, 0.f, 0.f);
    #pragma unroll
    for (int i = 0; i < 4; ++i) {
        const int r = tr * 4 + i;
        float4 v;
        v.x = fmaxf(accg[i].x + bgv.x, 0.f) + fmaxf(accr[i].x + brv.x, 0.f);
        v.y = fmaxf(accg[i].y + bgv.y, 0.f) + fmaxf(accr[i].y + brv.y, 0.f);
        v.z = fmaxf(accg[i].z + bgv.z, 0.f) + fmaxf(accr[i].z + brv.z, 0.f);
        v.w = fmaxf(accg[i].w + bgv.w, 0.f) + fmaxf(accr[i].w + brv.w, 0.f);
        *(float4*)(h2out + (size_t)(r0 + r) * DD + c0) = v;
        s.x += v.x; s.y += v.y; s.z += v.z; s.w += v.w;
        s2.x += v.x * v.x; s2.y += v.y * v.y; s2.z += v.z * v.z; s2.w += v.w * v.w;
    }
    s.x += __shfl_xor(s.x, 32, 64);   s.y += __shfl_xor(s.y, 32, 64);
    s.z += __shfl_xor(s.z, 32, 64);   s.w += __shfl_xor(s.w, 32, 64);
    s2.x += __shfl_xor(s2.x, 32, 64); s2.y += __shfl_xor(s2.y, 32, 64);
    s2.z += __shfl_xor(s2.z, 32, 64); s2.w += __shfl_xor(s2.w, 32, 64);
    if ((tid & 63) < 32) {
        atomicAdd(&sSum[c0 + 0], s.x);  atomicAdd(&sSum[c0 + 1], s.y);
        atomicAdd(&sSum[c0 + 2], s.z);  atomicAdd(&sSum[c0 + 3], s.w);
        atomicAdd(&sSum[128 + c0 + 0], s2.x); atomicAdd(&sSum[128 + c0 + 1], s2.y);
        atomicAdd(&sSum[128 + c0 + 2], s2.z); atomicAdd(&sSum[128 + c0 + 3], s2.w);
    }
    __syncthreads();
    atomicAdd(&sums[tid], sSum[tid]);   // sums layout: [s(128) | s2(128)]
}

// ---------------- BatchNorm normalize ----------------
__global__ __launch_bounds__(256) void k_bn(const float* __restrict__ h2,
                                            const float* __restrict__ sums,
                                            const float* __restrict__ gamma,
                                            const float* __restrict__ beta,
                                            float* __restrict__ out) {
    const int t = blockIdx.x * 256 + threadIdx.x;  // NN*32 threads
    const size_t base = (size_t)t * 4;
    const int c = (int)(base & 127);
    const float4 v = *(const float4*)(h2 + base);
    const float4 s = *(const float4*)(sums + c);
    const float4 s2 = *(const float4*)(sums + DD + c);
    const float4 g = *(const float4*)(gamma + c);
    const float4 b = *(const float4*)(beta + c);
    const float invN = 1.0f / (float)NN;
    float4 o;
    {
        float mu = s.x * invN; float var = s2.x * invN - mu * mu;
        o.x = (v.x - mu) * (g.x * rsqrtf(var + EPS)) + b.x;
    }
    {
        float mu = s.y * invN; float var = s2.y * invN - mu * mu;
        o.y = (v.y - mu) * (g.y * rsqrtf(var + EPS)) + b.y;
    }
    {
        float mu = s.z * invN; float var = s2.z * invN - mu * mu;
        o.z = (v.z - mu) * (g.z * rsqrtf(var + EPS)) + b.z;
    }
    {
        float mu = s.w * invN; float var = s2.w * invN - mu * mu;
        o.w = (v.w - mu) * (g.w * rsqrtf(var + EPS)) + b.w;
    }
    *(float4*)(out + base) = o;
}

extern "C" void kernel_launch(void* const* d_in, const int* in_sizes, int n_in,
                              void* d_out, int out_size, void* d_ws, size_t ws_size,
                              hipStream_t stream) {
    const float* X     = (const float*)d_in[0];
    const int*   src   = (const int*)d_in[1];
    const int*   dst   = (const int*)d_in[2];
    const float* Wi    = (const float*)d_in[3];
    const float* Wg    = (const float*)d_in[4];
    const float* bg    = (const float*)d_in[5];
    const float* Wr    = (const float*)d_in[6];
    const float* br    = (const float*)d_in[7];
    const float* gamma = (const float*)d_in[8];
    const float* beta  = (const float*)d_in[9];
    float* out = (float*)d_out;

    float* h    = (float*)d_ws;                       // [NN*DD]
    float* agg  = h + (size_t)NN * DD;                // [NN*DD]
    float* sums = agg + (size_t)NN * DD;              // [NL*2*DD]
    int* rowptr = (int*)(sums + NL * 2 * DD);         // [NN+1]
    int* col    = rowptr + NN + 1;                    // [NE]
    int* bsum   = col + NE;                           // [NB]
    int* boff   = bsum + NB;                          // [NB]
    // CSR-build scratch aliased into agg (dead once k_fill completes)
    int* cnt    = (int*)agg;                          // [NN]
    int* offs   = cnt + NN;                           // [NN]
    float* h2   = out;                                // reuse d_out as h2 scratch

    hipMemsetAsync(sums, 0, NL * 2 * DD * sizeof(float), stream);
    hipMemsetAsync(cnt, 0, NN * sizeof(int), stream);

    k_init<<<NN / 64, 64, 0, stream>>>(X, Wi, h);
    k_hist<<<NE / 256, 256, 0, stream>>>(dst, cnt);
    k_scan1<<<NB, 256, 0, stream>>>(cnt, bsum);
    k_scan2<<<1, 512, 0, stream>>>(bsum, boff);
    k_scan3<<<NB, 256, 0, stream>>>(cnt, boff, rowptr, offs);
    k_fill<<<NE / 256, 256, 0, stream>>>(src, dst, offs, col);

    for (int l = 0; l < NL; ++l) {
        k_gather<<<NN / 4, 256, 0, stream>>>(h, rowptr, col, agg);
        k_layer<<<NN / 32, 256, 0, stream>>>(h, agg,
                                             Wg + l * DD * DD, bg + l * DD,
                                             Wr + l * DD * DD, br + l * DD,
                                             h2, sums + l * 2 * DD);
        float* outp = (l == NL - 1) ? out : h;
        k_bn<<<(NN * 32) / 256, 256, 0, stream>>>(h2, sums + l * 2 * DD,
                                                  gamma + l * DD, beta + l * DD, outp);
    }
}

// Round 7
// 638.037 us; speedup vs baseline: 7.7275x; 1.0438x over previous
//
#include <hip/hip_runtime.h>

#define NN 74240      // nodes
#define NE 593920     // edges
#define DIN 75
#define DD 128
#define NL 3
#define EPS 1e-5f
#define NB 290        // scan blocks: 290*256 == NN

// ---------------- init GEMM: h = X @ W_init  ([NN,75] @ [75,128]) ----------------
__global__ __launch_bounds__(64) void k_init(const float* __restrict__ X,
                                             const float* __restrict__ W,
                                             float* __restrict__ h) {
    __shared__ float sX[64 * 77];
    const int r0 = blockIdx.x * 64;
    const int lane = threadIdx.x;
    const float* Xb = X + (size_t)r0 * DIN;
    for (int e = lane; e < 64 * DIN; e += 64) {
        int r = e / DIN;
        int k = e - r * DIN;
        sX[r * 77 + k] = Xb[e];
    }
    __syncthreads();
    float* hrow = h + (size_t)(r0 + lane) * DD;
    const float* xr = &sX[lane * 77];
    for (int ct = 0; ct < 8; ++ct) {
        const int c0 = ct * 16;
        float acc[16];
        #pragma unroll
        for (int j = 0; j < 16; ++j) acc[j] = 0.0f;
        #pragma unroll 5
        for (int k = 0; k < DIN; ++k) {
            const float a = xr[k];
            const float* wk = W + k * DD + c0;
            #pragma unroll
            for (int j = 0; j < 16; ++j)
                acc[j] = fmaf(a, wk[j], acc[j]);
        }
        #pragma unroll
        for (int j = 0; j < 16; ++j) hrow[c0 + j] = acc[j];
    }
}

// ---------------- CSR build: histogram -> 3-phase scan -> fill ----------------
__global__ __launch_bounds__(256) void k_hist(const int* __restrict__ dst, int* cnt) {
    const int e = blockIdx.x * 256 + threadIdx.x;   // grid == NE
    atomicAdd(&cnt[dst[e]], 1);
}

__global__ __launch_bounds__(256) void k_scan1(const int* __restrict__ cnt,
                                               int* __restrict__ bsum) {
    const int tid = threadIdx.x;
    int v = cnt[blockIdx.x * 256 + tid];
    #pragma unroll
    for (int off = 1; off < 64; off <<= 1) v += __shfl_xor(v, off, 64);
    __shared__ int ws[4];
    if ((tid & 63) == 0) ws[tid >> 6] = v;
    __syncthreads();
    if (tid == 0) bsum[blockIdx.x] = ws[0] + ws[1] + ws[2] + ws[3];
}

__global__ __launch_bounds__(512) void k_scan2(const int* __restrict__ bsum,
                                               int* __restrict__ boff) {
    __shared__ int s[512];
    const int t = threadIdx.x;
    const int v = (t < NB) ? bsum[t] : 0;
    s[t] = v;
    __syncthreads();
    for (int off = 1; off < 512; off <<= 1) {
        const int u = (t >= off) ? s[t - off] : 0;
        __syncthreads();
        s[t] += u;
        __syncthreads();
    }
    if (t < NB) boff[t] = s[t] - v;   // exclusive
}

__global__ __launch_bounds__(256) void k_scan3(const int* __restrict__ cnt,
                                               const int* __restrict__ boff,
                                               int* __restrict__ rowptr,
                                               int* __restrict__ offs) {
    const int tid = threadIdx.x;
    const int t = blockIdx.x * 256 + tid;
    const int lane = tid & 63;
    const int v = cnt[t];
    int inc = v;
    #pragma unroll
    for (int off = 1; off < 64; off <<= 1) {
        const int u = __shfl_up(inc, off, 64);
        if (lane >= off) inc += u;
    }
    __shared__ int ws[4];
    if (lane == 63) ws[tid >> 6] = inc;
    __syncthreads();
    const int w = tid >> 6;
    int waveoff = 0;
    for (int i = 0; i < 4; ++i) waveoff += (i < w) ? ws[i] : 0;
    const int excl = boff[blockIdx.x] + waveoff + inc - v;
    rowptr[t] = excl;
    offs[t] = excl;
    if (blockIdx.x == NB - 1 && tid == 255) rowptr[NN] = NE;
}

__global__ __launch_bounds__(256) void k_fill(const int* __restrict__ src,
                                              const int* __restrict__ dst,
                                              int* offs, int* __restrict__ col) {
    const int e = blockIdx.x * 256 + threadIdx.x;   // grid == NE
    const int pos = atomicAdd(&offs[dst[e]], 1);
    col[pos] = src[e];
}

// ---------------- BN affine-coefficient helpers ----------------
// ab[c] = a (scale), ab[128+c] = b (shift): h_norm = a*h_raw + b
__global__ __launch_bounds__(256) void k_prep(float* __restrict__ ab0) {
    ab0[threadIdx.x] = (threadIdx.x < 128) ? 1.0f : 0.0f;   // identity for layer 0 input
}

__global__ __launch_bounds__(128) void k_stats(const float* __restrict__ sums,
                                               const float* __restrict__ gamma,
                                               const float* __restrict__ beta,
                                               float* __restrict__ ab) {
    const int c = threadIdx.x;
    const float invN = 1.0f / (float)NN;
    const float mu = sums[c] * invN;
    const float var = sums[128 + c] * invN - mu * mu;
    const float a = gamma[c] * rsqrtf(var + EPS);
    ab[c] = a;
    ab[128 + c] = beta[c] - a * mu;
}

// ---------------- gather (BN folded): agg[row] = a * sum_e h_raw[col[e]] + deg*b ----
__global__ __launch_bounds__(256) void k_gather(const float* __restrict__ h,
                                                const int* __restrict__ rowptr,
                                                const int* __restrict__ col,
                                                const float* __restrict__ ab,
                                                float* __restrict__ agg) {
    const int wave = threadIdx.x >> 6;
    const int lane = threadIdx.x & 63;
    const int row = blockIdx.x * 4 + wave;   // grid = NN/4
    const int eb = rowptr[row];
    const int ee = rowptr[row + 1];
    const int half = lane >> 5;
    const int f = (lane & 31) * 4;
    float4 a0 = {0.f,0.f,0.f,0.f}, a1 = {0.f,0.f,0.f,0.f};
    float4 a2 = {0.f,0.f,0.f,0.f}, a3 = {0.f,0.f,0.f,0.f};
    int e = eb + half;
    for (; e + 6 < ee; e += 8) {
        const int c0 = col[e], c1 = col[e + 2], c2 = col[e + 4], c3 = col[e + 6];
        const float4 v0 = *(const float4*)(h + (size_t)c0 * DD + f);
        const float4 v1 = *(const float4*)(h + (size_t)c1 * DD + f);
        const float4 v2 = *(const float4*)(h + (size_t)c2 * DD + f);
        const float4 v3 = *(const float4*)(h + (size_t)c3 * DD + f);
        a0.x += v0.x; a0.y += v0.y; a0.z += v0.z; a0.w += v0.w;
        a1.x += v1.x; a1.y += v1.y; a1.z += v1.z; a1.w += v1.w;
        a2.x += v2.x; a2.y += v2.y; a2.z += v2.z; a2.w += v2.w;
        a3.x += v3.x; a3.y += v3.y; a3.z += v3.z; a3.w += v3.w;
    }
    for (; e < ee; e += 2) {
        const int c = col[e];
        const float4 v = *(const float4*)(h + (size_t)c * DD + f);
        a0.x += v.x; a0.y += v.y; a0.z += v.z; a0.w += v.w;
    }
    float4 s;
    s.x = (a0.x + a1.x) + (a2.x + a3.x);
    s.y = (a0.y + a1.y) + (a2.y + a3.y);
    s.z = (a0.z + a1.z) + (a2.z + a3.z);
    s.w = (a0.w + a1.w) + (a2.w + a3.w);
    s.x += __shfl_xor(s.x, 32, 64);
    s.y += __shfl_xor(s.y, 32, 64);
    s.z += __shfl_xor(s.z, 32, 64);
    s.w += __shfl_xor(s.w, 32, 64);
    if (half == 0) {
        const float deg = (float)(ee - eb);
        const float4 av = *(const float4*)(ab + f);
        const float4 bv = *(const float4*)(ab + 128 + f);
        float4 o;
        o.x = fmaf(av.x, s.x, deg * bv.x);
        o.y = fmaf(av.y, s.y, deg * bv.y);
        o.z = fmaf(av.z, s.z, deg * bv.z);
        o.w = fmaf(av.w, s.w, deg * bv.w);
        *(float4*)(agg + (size_t)row * DD + f) = o;
    }
}

// ---------------- fused layer GEMMs (register-tiled, 16-row weight chunks) -------
// Block: 32 rows x 128 cols. Thread (tr,tc) owns 4x4 tile of both GEMMs.
// LDS: sA/sH 33 KB + sW 16 KB + sSum 1 KB = 50 KB -> 3 blocks/CU (was 2 at 67.5 KB).
// sH staging applies the folded-BN affine (a,b) of the previous layer.
#define LA 132
__global__ __launch_bounds__(256, 3) void k_layer(const float* __restrict__ hin,
                                                  const float* __restrict__ aggin,
                                                  const float* __restrict__ Wg,
                                                  const float* __restrict__ bg,
                                                  const float* __restrict__ Wr,
                                                  const float* __restrict__ br,
                                                  const float* __restrict__ ab,
                                                  float* __restrict__ h2out,
                                                  float* sums) {
    __shared__ float sA[32 * LA];
    __shared__ float sH[32 * LA];
    __shared__ float sWg[16 * 128];
    __shared__ float sWr[16 * 128];
    __shared__ float sSum[256];
    const int tid = threadIdx.x;
    const int r0 = blockIdx.x * 32;
    const int tr = tid >> 5;          // 0..7
    const int tc = tid & 31;          // 0..31
    const int c0 = tc * 4;

    {
        const float4* A4 = (const float4*)(aggin + (size_t)r0 * DD);
        const float4* H4 = (const float4*)(hin + (size_t)r0 * DD);
        #pragma unroll
        for (int it = 0; it < 4; ++it) {
            const int idx4 = tid + it * 256;
            const int r = idx4 >> 5;
            const int kc = (idx4 & 31) * 4;
            *(float4*)&sA[r * LA + kc] = A4[idx4];     // agg already normalized by k_gather
            const float4 hh = H4[idx4];
            const float4 av = *(const float4*)(ab + kc);
            const float4 bv = *(const float4*)(ab + 128 + kc);
            float* ph = &sH[r * LA + kc];
            ph[0] = fmaf(av.x, hh.x, bv.x);
            ph[1] = fmaf(av.y, hh.y, bv.y);
            ph[2] = fmaf(av.z, hh.z, bv.z);
            ph[3] = fmaf(av.w, hh.w, bv.w);
        }
        sSum[tid] = 0.0f;
    }

    float4 accg[4], accr[4];
    #pragma unroll
    for (int i = 0; i < 4; ++i) {
        accg[i] = make_float4(0.f, 0.f, 0.f, 0.f);
        accr[i] = make_float4(0.f, 0.f, 0.f, 0.f);
    }

    for (int kb = 0; kb < 8; ++kb) {
        __syncthreads();
        {
            const float4* G4 = (const float4*)(Wg + kb * 16 * DD);
            const float4* R4 = (const float4*)(Wr + kb * 16 * DD);
            ((float4*)sWg)[tid]       = G4[tid];
            ((float4*)sWg)[tid + 256] = G4[tid + 256];
            ((float4*)sWr)[tid]       = R4[tid];
            ((float4*)sWr)[tid + 256] = R4[tid + 256];
        }
        __syncthreads();
        const int kbase = kb * 16;
        #pragma unroll
        for (int k4 = 0; k4 < 16; k4 += 4) {
            float4 wg[4], wr[4];
            #pragma unroll
            for (int kk = 0; kk < 4; ++kk) {
                wg[kk] = *(const float4*)&sWg[(k4 + kk) * 128 + c0];
                wr[kk] = *(const float4*)&sWr[(k4 + kk) * 128 + c0];
            }
            #pragma unroll
            for (int i = 0; i < 4; ++i) {
                const int r = tr * 4 + i;
                const float4 av = *(const float4*)&sA[r * LA + kbase + k4];
                const float4 hv = *(const float4*)&sH[r * LA + kbase + k4];
                accg[i].x = fmaf(av.x, wg[0].x, accg[i].x); accg[i].y = fmaf(av.x, wg[0].y, accg[i].y);
                accg[i].z = fmaf(av.x, wg[0].z, accg[i].z); accg[i].w = fmaf(av.x, wg[0].w, accg[i].w);
                accg[i].x = fmaf(av.y, wg[1].x, accg[i].x); accg[i].y = fmaf(av.y, wg[1].y, accg[i].y);
                accg[i].z = fmaf(av.y, wg[1].z, accg[i].z); accg[i].w = fmaf(av.y, wg[1].w, accg[i].w);
                accg[i].x = fmaf(av.z, wg[2].x, accg[i].x); accg[i].y = fmaf(av.z, wg[2].y, accg[i].y);
                accg[i].z = fmaf(av.z, wg[2].z, accg[i].z); accg[i].w = fmaf(av.z, wg[2].w, accg[i].w);
                accg[i].x = fmaf(av.w, wg[3].x, accg[i].x); accg[i].y = fmaf(av.w, wg[3].y, accg[i].y);
                accg[i].z = fmaf(av.w, wg[3].z, accg[i].z); accg[i].w = fmaf(av.w, wg[3].w, accg[i].w);
                accr[i].x = fmaf(hv.x, wr[0].x, accr[i].x); accr[i].y = fmaf(hv.x, wr[0].y, accr[i].y);
                accr[i].z = fmaf(hv.x, wr[0].z, accr[i].z); accr[i].w = fmaf(hv.x, wr[0].w, accr[i].w);
                accr[i].x = fmaf(hv.y, wr[1].x, accr[i].x); accr[i].y = fmaf(hv.y, wr[1].y, accr[i].y);
                accr[i].z = fmaf(hv.y, wr[1].z, accr[i].z); accr[i].w = fmaf(hv.y, wr[1].w, accr[i].w);
                accr[i].x = fmaf(hv.z, wr[2].x, accr[i].x); accr[i].y = fmaf(hv.z, wr[2].y, accr[i].y);
                accr[i].z = fmaf(hv.z, wr[2].z, accr[i].z); accr[i].w = fmaf(hv.z, wr[2].w, accr[i].w);
                accr[i].x = fmaf(hv.w, wr[3].x, accr[i].x); accr[i].y = fmaf(hv.w, wr[3].y, accr[i].y);
                accr[i].z = fmaf(hv.w, wr[3].z, accr[i].z); accr[i].w = fmaf(hv.w, wr[3].w, accr[i].w);
            }
        }
    }

    const float4 bgv = *(const float4*)(bg + c0);
    const float4 brv = *(const float4*)(br + c0);
    float4 s = make_float4(0.f, 0.f, 0.f, 0.f);
    float4 s2 = make_float4(0.f, 0.f, 0.f, 0.f);
    #pragma unroll
    for (int i = 0; i < 4; ++i) {
        const int r = tr * 4 + i;
        float4 v;
        v.x = fmaxf(accg[i].x + bgv.x, 0.f) + fmaxf(accr[i].x + brv.x, 0.f);
        v.y = fmaxf(accg[i].y + bgv.y, 0.f) + fmaxf(accr[i].y + brv.y, 0.f);
        v.z = fmaxf(accg[i].z + bgv.z, 0.f) + fmaxf(accr[i].z + brv.z, 0.f);
        v.w = fmaxf(accg[i].w + bgv.w, 0.f) + fmaxf(accr[i].w + brv.w, 0.f);
        *(float4*)(h2out + (size_t)(r0 + r) * DD + c0) = v;
        s.x += v.x; s.y += v.y; s.z += v.z; s.w += v.w;
        s2.x += v.x * v.x; s2.y += v.y * v.y; s2.z += v.z * v.z; s2.w += v.w * v.w;
    }
    s.x += __shfl_xor(s.x, 32, 64);   s.y += __shfl_xor(s.y, 32, 64);
    s.z += __shfl_xor(s.z, 32, 64);   s.w += __shfl_xor(s.w, 32, 64);
    s2.x += __shfl_xor(s2.x, 32, 64); s2.y += __shfl_xor(s2.y, 32, 64);
    s2.z += __shfl_xor(s2.z, 32, 64); s2.w += __shfl_xor(s2.w, 32, 64);
    if ((tid & 63) < 32) {
        atomicAdd(&sSum[c0 + 0], s.x);  atomicAdd(&sSum[c0 + 1], s.y);
        atomicAdd(&sSum[c0 + 2], s.z);  atomicAdd(&sSum[c0 + 3], s.w);
        atomicAdd(&sSum[128 + c0 + 0], s2.x); atomicAdd(&sSum[128 + c0 + 1], s2.y);
        atomicAdd(&sSum[128 + c0 + 2], s2.z); atomicAdd(&sSum[128 + c0 + 3], s2.w);
    }
    __syncthreads();
    atomicAdd(&sums[tid], sSum[tid]);   // sums layout: [s(128) | s2(128)]
}

// ---------------- BatchNorm normalize (final layer only, in-place capable) -------
__global__ __launch_bounds__(256) void k_bn(const float* __restrict__ h2,
                                            const float* __restrict__ sums,
                                            const float* __restrict__ gamma,
                                            const float* __restrict__ beta,
                                            float* __restrict__ out) {
    const int t = blockIdx.x * 256 + threadIdx.x;  // NN*32 threads
    const size_t base = (size_t)t * 4;
    const int c = (int)(base & 127);
    const float4 v = *(const float4*)(h2 + base);
    const float4 s = *(const float4*)(sums + c);
    const float4 s2 = *(const float4*)(sums + DD + c);
    const float4 g = *(const float4*)(gamma + c);
    const float4 b = *(const float4*)(beta + c);
    const float invN = 1.0f / (float)NN;
    float4 o;
    {
        float mu = s.x * invN; float var = s2.x * invN - mu * mu;
        o.x = (v.x - mu) * (g.x * rsqrtf(var + EPS)) + b.x;
    }
    {
        float mu = s.y * invN; float var = s2.y * invN - mu * mu;
        o.y = (v.y - mu) * (g.y * rsqrtf(var + EPS)) + b.y;
    }
    {
        float mu = s.z * invN; float var = s2.z * invN - mu * mu;
        o.z = (v.z - mu) * (g.z * rsqrtf(var + EPS)) + b.z;
    }
    {
        float mu = s.w * invN; float var = s2.w * invN - mu * mu;
        o.w = (v.w - mu) * (g.w * rsqrtf(var + EPS)) + b.w;
    }
    *(float4*)(out + base) = o;
}

extern "C" void kernel_launch(void* const* d_in, const int* in_sizes, int n_in,
                              void* d_out, int out_size, void* d_ws, size_t ws_size,
                              hipStream_t stream) {
    const float* X     = (const float*)d_in[0];
    const int*   src   = (const int*)d_in[1];
    const int*   dst   = (const int*)d_in[2];
    const float* Wi    = (const float*)d_in[3];
    const float* Wg    = (const float*)d_in[4];
    const float* bg    = (const float*)d_in[5];
    const float* Wr    = (const float*)d_in[6];
    const float* br    = (const float*)d_in[7];
    const float* gamma = (const float*)d_in[8];
    const float* beta  = (const float*)d_in[9];
    float* out = (float*)d_out;

    float* h    = (float*)d_ws;                       // [NN*DD]
    float* agg  = h + (size_t)NN * DD;                // [NN*DD]
    float* sums = agg + (size_t)NN * DD;              // [NL*2*DD]
    float* abv  = sums + NL * 2 * DD;                 // [NL*2*DD]  a/b per layer input
    int* rowptr = (int*)(abv + NL * 2 * DD);          // [NN+1]
    int* col    = rowptr + NN + 1;                    // [NE]
    int* bsum   = col + NE;                           // [NB]
    int* boff   = bsum + NB;                          // [NB]
    // CSR-build scratch aliased into agg (dead once k_fill completes)
    int* cnt    = (int*)agg;                          // [NN]
    int* offs   = cnt + NN;                           // [NN]

    hipMemsetAsync(sums, 0, NL * 2 * DD * sizeof(float), stream);
    hipMemsetAsync(cnt, 0, NN * sizeof(int), stream);

    k_prep<<<1, 256, 0, stream>>>(abv);               // identity a=1,b=0 for layer 0
    k_init<<<NN / 64, 64, 0, stream>>>(X, Wi, h);
    k_hist<<<NE / 256, 256, 0, stream>>>(dst, cnt);
    k_scan1<<<NB, 256, 0, stream>>>(cnt, bsum);
    k_scan2<<<1, 512, 0, stream>>>(bsum, boff);
    k_scan3<<<NB, 256, 0, stream>>>(cnt, boff, rowptr, offs);
    k_fill<<<NE / 256, 256, 0, stream>>>(src, dst, offs, col);

    // raw-activation buffers alternate: h -> out -> h -> out (final BN in-place on out)
    const float* hcur = h;
    float* h2bufs[NL] = { out, h, out };
    for (int l = 0; l < NL; ++l) {
        const float* abl = abv + l * 2 * DD;
        float* h2 = h2bufs[l];
        k_gather<<<NN / 4, 256, 0, stream>>>(hcur, rowptr, col, abl, agg);
        k_layer<<<NN / 32, 256, 0, stream>>>(hcur, agg,
                                             Wg + l * DD * DD, bg + l * DD,
                                             Wr + l * DD * DD, br + l * DD,
                                             abl, h2, sums + l * 2 * DD);
        if (l < NL - 1) {
            k_stats<<<1, 128, 0, stream>>>(sums + l * 2 * DD, gamma + l * DD,
                                           beta + l * DD, abv + (l + 1) * 2 * DD);
        } else {
            k_bn<<<(NN * 32) / 256, 256, 0, stream>>>(h2, sums + l * 2 * DD,
                                                      gamma + l * DD, beta + l * DD, out);
        }
        hcur = h2;
    }
}

// Round 8
// 627.502 us; speedup vs baseline: 7.8573x; 1.0168x over previous
//
#include <hip/hip_runtime.h>

#define NN 74240      // nodes
#define NE 593920     // edges
#define DIN 75
#define DD 128
#define NL 3
#define EPS 1e-5f
#define NB 290        // scan blocks: 290*256 == NN

// ---------------- init GEMM: h = X @ W_init  ([NN,75] @ [75,128]) ----------------
__global__ __launch_bounds__(64) void k_init(const float* __restrict__ X,
                                             const float* __restrict__ W,
                                             float* __restrict__ h) {
    __shared__ float sX[64 * 77];
    const int r0 = blockIdx.x * 64;
    const int lane = threadIdx.x;
    const float* Xb = X + (size_t)r0 * DIN;
    for (int e = lane; e < 64 * DIN; e += 64) {
        int r = e / DIN;
        int k = e - r * DIN;
        sX[r * 77 + k] = Xb[e];
    }
    __syncthreads();
    float* hrow = h + (size_t)(r0 + lane) * DD;
    const float* xr = &sX[lane * 77];
    for (int ct = 0; ct < 8; ++ct) {
        const int c0 = ct * 16;
        float acc[16];
        #pragma unroll
        for (int j = 0; j < 16; ++j) acc[j] = 0.0f;
        #pragma unroll 5
        for (int k = 0; k < DIN; ++k) {
            const float a = xr[k];
            const float* wk = W + k * DD + c0;
            #pragma unroll
            for (int j = 0; j < 16; ++j)
                acc[j] = fmaf(a, wk[j], acc[j]);
        }
        #pragma unroll
        for (int j = 0; j < 16; ++j) hrow[c0 + j] = acc[j];
    }
}

// ---------------- CSR build: histogram -> 3-phase scan -> fill ----------------
__global__ __launch_bounds__(256) void k_hist(const int* __restrict__ dst, int* cnt) {
    const int e = blockIdx.x * 256 + threadIdx.x;   // grid == NE
    atomicAdd(&cnt[dst[e]], 1);
}

__global__ __launch_bounds__(256) void k_scan1(const int* __restrict__ cnt,
                                               int* __restrict__ bsum) {
    const int tid = threadIdx.x;
    int v = cnt[blockIdx.x * 256 + tid];
    #pragma unroll
    for (int off = 1; off < 64; off <<= 1) v += __shfl_xor(v, off, 64);
    __shared__ int ws[4];
    if ((tid & 63) == 0) ws[tid >> 6] = v;
    __syncthreads();
    if (tid == 0) bsum[blockIdx.x] = ws[0] + ws[1] + ws[2] + ws[3];
}

__global__ __launch_bounds__(512) void k_scan2(const int* __restrict__ bsum,
                                               int* __restrict__ boff) {
    __shared__ int s[512];
    const int t = threadIdx.x;
    const int v = (t < NB) ? bsum[t] : 0;
    s[t] = v;
    __syncthreads();
    for (int off = 1; off < 512; off <<= 1) {
        const int u = (t >= off) ? s[t - off] : 0;
        __syncthreads();
        s[t] += u;
        __syncthreads();
    }
    if (t < NB) boff[t] = s[t] - v;   // exclusive
}

__global__ __launch_bounds__(256) void k_scan3(const int* __restrict__ cnt,
                                               const int* __restrict__ boff,
                                               int* __restrict__ rowptr,
                                               int* __restrict__ offs) {
    const int tid = threadIdx.x;
    const int t = blockIdx.x * 256 + tid;
    const int lane = tid & 63;
    const int v = cnt[t];
    int inc = v;
    #pragma unroll
    for (int off = 1; off < 64; off <<= 1) {
        const int u = __shfl_up(inc, off, 64);
        if (lane >= off) inc += u;
    }
    __shared__ int ws[4];
    if (lane == 63) ws[tid >> 6] = inc;
    __syncthreads();
    const int w = tid >> 6;
    int waveoff = 0;
    for (int i = 0; i < 4; ++i) waveoff += (i < w) ? ws[i] : 0;
    const int excl = boff[blockIdx.x] + waveoff + inc - v;
    rowptr[t] = excl;
    offs[t] = excl;
    if (blockIdx.x == NB - 1 && tid == 255) rowptr[NN] = NE;
}

__global__ __launch_bounds__(256) void k_fill(const int* __restrict__ src,
                                              const int* __restrict__ dst,
                                              int* offs, int* __restrict__ col) {
    const int e = blockIdx.x * 256 + threadIdx.x;   // grid == NE
    const int pos = atomicAdd(&offs[dst[e]], 1);
    col[pos] = src[e];
}

// ---------------- BN affine-coefficient helpers ----------------
__global__ __launch_bounds__(256) void k_prep(float* __restrict__ ab0) {
    ab0[threadIdx.x] = (threadIdx.x < 128) ? 1.0f : 0.0f;   // identity for layer 0 input
}

__global__ __launch_bounds__(128) void k_stats(const float* __restrict__ sums,
                                               const float* __restrict__ gamma,
                                               const float* __restrict__ beta,
                                               float* __restrict__ ab) {
    const int c = threadIdx.x;
    const float invN = 1.0f / (float)NN;
    const float mu = sums[c] * invN;
    const float var = sums[128 + c] * invN - mu * mu;
    const float a = gamma[c] * rsqrtf(var + EPS);
    ab[c] = a;
    ab[128 + c] = beta[c] - a * mu;
}

// ---------------- gather (BN folded): agg[row] = a * sum_e h_raw[col[e]] + deg*b ----
__global__ __launch_bounds__(256) void k_gather(const float* __restrict__ h,
                                                const int* __restrict__ rowptr,
                                                const int* __restrict__ col,
                                                const float* __restrict__ ab,
                                                float* __restrict__ agg) {
    const int wave = threadIdx.x >> 6;
    const int lane = threadIdx.x & 63;
    const int row = blockIdx.x * 4 + wave;   // grid = NN/4
    const int eb = rowptr[row];
    const int ee = rowptr[row + 1];
    const int half = lane >> 5;
    const int f = (lane & 31) * 4;
    float4 a0 = {0.f,0.f,0.f,0.f}, a1 = {0.f,0.f,0.f,0.f};
    float4 a2 = {0.f,0.f,0.f,0.f}, a3 = {0.f,0.f,0.f,0.f};
    int e = eb + half;
    for (; e + 6 < ee; e += 8) {
        const int c0 = col[e], c1 = col[e + 2], c2 = col[e + 4], c3 = col[e + 6];
        const float4 v0 = *(const float4*)(h + (size_t)c0 * DD + f);
        const float4 v1 = *(const float4*)(h + (size_t)c1 * DD + f);
        const float4 v2 = *(const float4*)(h + (size_t)c2 * DD + f);
        const float4 v3 = *(const float4*)(h + (size_t)c3 * DD + f);
        a0.x += v0.x; a0.y += v0.y; a0.z += v0.z; a0.w += v0.w;
        a1.x += v1.x; a1.y += v1.y; a1.z += v1.z; a1.w += v1.w;
        a2.x += v2.x; a2.y += v2.y; a2.z += v2.z; a2.w += v2.w;
        a3.x += v3.x; a3.y += v3.y; a3.z += v3.z; a3.w += v3.w;
    }
    for (; e < ee; e += 2) {
        const int c = col[e];
        const float4 v = *(const float4*)(h + (size_t)c * DD + f);
        a0.x += v.x; a0.y += v.y; a0.z += v.z; a0.w += v.w;
    }
    float4 s;
    s.x = (a0.x + a1.x) + (a2.x + a3.x);
    s.y = (a0.y + a1.y) + (a2.y + a3.y);
    s.z = (a0.z + a1.z) + (a2.z + a3.z);
    s.w = (a0.w + a1.w) + (a2.w + a3.w);
    s.x += __shfl_xor(s.x, 32, 64);
    s.y += __shfl_xor(s.y, 32, 64);
    s.z += __shfl_xor(s.z, 32, 64);
    s.w += __shfl_xor(s.w, 32, 64);
    if (half == 0) {
        const float deg = (float)(ee - eb);
        const float4 av = *(const float4*)(ab + f);
        const float4 bv = *(const float4*)(ab + 128 + f);
        float4 o;
        o.x = fmaf(av.x, s.x, deg * bv.x);
        o.y = fmaf(av.y, s.y, deg * bv.y);
        o.z = fmaf(av.z, s.z, deg * bv.z);
        o.w = fmaf(av.w, s.w, deg * bv.w);
        *(float4*)(agg + (size_t)row * DD + f) = o;
    }
}

// ---------------- fused layer GEMMs: 128x128 block, 8x8 register tile ----------------
// 256 threads: tr=tid>>4 (16 row-groups of 8), tc=tid&15; thread cols = {tc*4..+4} u {64+tc*4..+4}
// (split cols -> W-reads 2-way bank-aliased = free; A/H transposed [k][row] -> 4 broadcast
// addresses per wave = conflict-free). A/H/W all streamed in 16-k LDS chunks.
// FMA per LDS byte = 1.0 (was 0.5) -> LDS pipe no longer 3x oversubscribed vs VALU.
#define LR 132   // 128 rows + 4 pad (keeps 16B alignment of k-rows)
__global__ __launch_bounds__(256, 2) void k_layer(const float* __restrict__ hin,
                                                  const float* __restrict__ aggin,
                                                  const float* __restrict__ Wg,
                                                  const float* __restrict__ bg,
                                                  const float* __restrict__ Wr,
                                                  const float* __restrict__ br,
                                                  const float* __restrict__ ab,
                                                  float* __restrict__ h2out,
                                                  float* sums) {
    __shared__ float sAk[16 * LR];    // [k][row], agg (already BN-folded by k_gather)
    __shared__ float sHk[16 * LR];    // [k][row], h with BN affine applied
    __shared__ float sWg[16 * 128];   // [k][col]
    __shared__ float sWr[16 * 128];
    __shared__ float sSum[256];
    const int tid = threadIdx.x;
    const int r0 = blockIdx.x * 128;
    const int tr = tid >> 4;          // 0..15 -> rows tr*8..+8
    const int tc = tid & 15;          // 0..15
    const int ca = tc * 4;            // col group 0
    const int cb = 64 + tc * 4;       // col group 1
    const int srow = tid >> 1;        // staging row 0..127
    const int sseg = tid & 1;         // k sub-chunk 0/1

    sSum[tid] = 0.0f;

    float4 accg[8][2], accr[8][2];
    #pragma unroll
    for (int i = 0; i < 8; ++i) {
        accg[i][0] = make_float4(0.f,0.f,0.f,0.f); accg[i][1] = make_float4(0.f,0.f,0.f,0.f);
        accr[i][0] = make_float4(0.f,0.f,0.f,0.f); accr[i][1] = make_float4(0.f,0.f,0.f,0.f);
    }

    for (int kb = 0; kb < 8; ++kb) {
        __syncthreads();
        {   // stage W chunk (plain copy, [k][col])
            const float4* G4 = (const float4*)(Wg + kb * 16 * DD);
            const float4* R4 = (const float4*)(Wr + kb * 16 * DD);
            ((float4*)sWg)[tid]       = G4[tid];
            ((float4*)sWg)[tid + 256] = G4[tid + 256];
            ((float4*)sWr)[tid]       = R4[tid];
            ((float4*)sWr)[tid + 256] = R4[tid + 256];
        }
        {   // stage A/H chunk transposed: sXk[k][row]; H gets BN affine
            const int kg = kb * 16 + sseg * 8;
            const float* arow = aggin + (size_t)(r0 + srow) * DD + kg;
            const float* hrow = hin + (size_t)(r0 + srow) * DD + kg;
            const float4 a0 = *(const float4*)(arow);
            const float4 a1 = *(const float4*)(arow + 4);
            const float4 h0 = *(const float4*)(hrow);
            const float4 h1 = *(const float4*)(hrow + 4);
            const float4 av0 = *(const float4*)(ab + kg);
            const float4 av1 = *(const float4*)(ab + kg + 4);
            const float4 bv0 = *(const float4*)(ab + 128 + kg);
            const float4 bv1 = *(const float4*)(ab + 128 + kg + 4);
            const int kl = sseg * 8;
            sAk[(kl+0)*LR + srow] = a0.x;  sAk[(kl+1)*LR + srow] = a0.y;
            sAk[(kl+2)*LR + srow] = a0.z;  sAk[(kl+3)*LR + srow] = a0.w;
            sAk[(kl+4)*LR + srow] = a1.x;  sAk[(kl+5)*LR + srow] = a1.y;
            sAk[(kl+6)*LR + srow] = a1.z;  sAk[(kl+7)*LR + srow] = a1.w;
            sHk[(kl+0)*LR + srow] = fmaf(av0.x, h0.x, bv0.x);
            sHk[(kl+1)*LR + srow] = fmaf(av0.y, h0.y, bv0.y);
            sHk[(kl+2)*LR + srow] = fmaf(av0.z, h0.z, bv0.z);
            sHk[(kl+3)*LR + srow] = fmaf(av0.w, h0.w, bv0.w);
            sHk[(kl+4)*LR + srow] = fmaf(av1.x, h1.x, bv1.x);
            sHk[(kl+5)*LR + srow] = fmaf(av1.y, h1.y, bv1.y);
            sHk[(kl+6)*LR + srow] = fmaf(av1.z, h1.z, bv1.z);
            sHk[(kl+7)*LR + srow] = fmaf(av1.w, h1.w, bv1.w);
        }
        __syncthreads();
        #pragma unroll 2
        for (int k = 0; k < 16; ++k) {
            const float4 wg0 = *(const float4*)&sWg[k * 128 + ca];
            const float4 wg1 = *(const float4*)&sWg[k * 128 + cb];
            const float4 wr0 = *(const float4*)&sWr[k * 128 + ca];
            const float4 wr1 = *(const float4*)&sWr[k * 128 + cb];
            const float4 a0 = *(const float4*)&sAk[k * LR + tr * 8];
            const float4 a1 = *(const float4*)&sAk[k * LR + tr * 8 + 4];
            const float4 h0 = *(const float4*)&sHk[k * LR + tr * 8];
            const float4 h1 = *(const float4*)&sHk[k * LR + tr * 8 + 4];
            #define ROWFMA(ri, aV, hV)                                              \
                accg[ri][0].x = fmaf(aV, wg0.x, accg[ri][0].x);                     \
                accg[ri][0].y = fmaf(aV, wg0.y, accg[ri][0].y);                     \
                accg[ri][0].z = fmaf(aV, wg0.z, accg[ri][0].z);                     \
                accg[ri][0].w = fmaf(aV, wg0.w, accg[ri][0].w);                     \
                accg[ri][1].x = fmaf(aV, wg1.x, accg[ri][1].x);                     \
                accg[ri][1].y = fmaf(aV, wg1.y, accg[ri][1].y);                     \
                accg[ri][1].z = fmaf(aV, wg1.z, accg[ri][1].z);                     \
                accg[ri][1].w = fmaf(aV, wg1.w, accg[ri][1].w);                     \
                accr[ri][0].x = fmaf(hV, wr0.x, accr[ri][0].x);                     \
                accr[ri][0].y = fmaf(hV, wr0.y, accr[ri][0].y);                     \
                accr[ri][0].z = fmaf(hV, wr0.z, accr[ri][0].z);                     \
                accr[ri][0].w = fmaf(hV, wr0.w, accr[ri][0].w);                     \
                accr[ri][1].x = fmaf(hV, wr1.x, accr[ri][1].x);                     \
                accr[ri][1].y = fmaf(hV, wr1.y, accr[ri][1].y);                     \
                accr[ri][1].z = fmaf(hV, wr1.z, accr[ri][1].z);                     \
                accr[ri][1].w = fmaf(hV, wr1.w, accr[ri][1].w);
            ROWFMA(0, a0.x, h0.x) ROWFMA(1, a0.y, h0.y)
            ROWFMA(2, a0.z, h0.z) ROWFMA(3, a0.w, h0.w)
            ROWFMA(4, a1.x, h1.x) ROWFMA(5, a1.y, h1.y)
            ROWFMA(6, a1.z, h1.z) ROWFMA(7, a1.w, h1.w)
            #undef ROWFMA
        }
    }

    // epilogue: bias + relu + add, store h2, BN partial sums
    const float4 bga = *(const float4*)(bg + ca);
    const float4 bgb = *(const float4*)(bg + cb);
    const float4 bra = *(const float4*)(br + ca);
    const float4 brb = *(const float4*)(br + cb);
    float4 sa = make_float4(0.f,0.f,0.f,0.f), sb = make_float4(0.f,0.f,0.f,0.f);
    float4 qa = make_float4(0.f,0.f,0.f,0.f), qb = make_float4(0.f,0.f,0.f,0.f);
    #pragma unroll
    for (int i = 0; i < 8; ++i) {
        const int row = r0 + tr * 8 + i;
        float4 v0, v1;
        v0.x = fmaxf(accg[i][0].x + bga.x, 0.f) + fmaxf(accr[i][0].x + bra.x, 0.f);
        v0.y = fmaxf(accg[i][0].y + bga.y, 0.f) + fmaxf(accr[i][0].y + bra.y, 0.f);
        v0.z = fmaxf(accg[i][0].z + bga.z, 0.f) + fmaxf(accr[i][0].z + bra.z, 0.f);
        v0.w = fmaxf(accg[i][0].w + bga.w, 0.f) + fmaxf(accr[i][0].w + bra.w, 0.f);
        v1.x = fmaxf(accg[i][1].x + bgb.x, 0.f) + fmaxf(accr[i][1].x + brb.x, 0.f);
        v1.y = fmaxf(accg[i][1].y + bgb.y, 0.f) + fmaxf(accr[i][1].y + brb.y, 0.f);
        v1.z = fmaxf(accg[i][1].z + bgb.z, 0.f) + fmaxf(accr[i][1].z + brb.z, 0.f);
        v1.w = fmaxf(accg[i][1].w + bgb.w, 0.f) + fmaxf(accr[i][1].w + brb.w, 0.f);
        *(float4*)(h2out + (size_t)row * DD + ca) = v0;
        *(float4*)(h2out + (size_t)row * DD + cb) = v1;
        sa.x += v0.x; sa.y += v0.y; sa.z += v0.z; sa.w += v0.w;
        sb.x += v1.x; sb.y += v1.y; sb.z += v1.z; sb.w += v1.w;
        qa.x += v0.x*v0.x; qa.y += v0.y*v0.y; qa.z += v0.z*v0.z; qa.w += v0.w*v0.w;
        qb.x += v1.x*v1.x; qb.y += v1.y*v1.y; qb.z += v1.z*v1.z; qb.w += v1.w*v1.w;
    }
    // reduce across the 4 tr-subgroups within the wave (lanes ^16, ^32); tc preserved
    #pragma unroll
    for (int off = 16; off <= 32; off <<= 1) {
        sa.x += __shfl_xor(sa.x, off, 64); sa.y += __shfl_xor(sa.y, off, 64);
        sa.z += __shfl_xor(sa.z, off, 64); sa.w += __shfl_xor(sa.w, off, 64);
        sb.x += __shfl_xor(sb.x, off, 64); sb.y += __shfl_xor(sb.y, off, 64);
        sb.z += __shfl_xor(sb.z, off, 64); sb.w += __shfl_xor(sb.w, off, 64);
        qa.x += __shfl_xor(qa.x, off, 64); qa.y += __shfl_xor(qa.y, off, 64);
        qa.z += __shfl_xor(qa.z, off, 64); qa.w += __shfl_xor(qa.w, off, 64);
        qb.x += __shfl_xor(qb.x, off, 64); qb.y += __shfl_xor(qb.y, off, 64);
        qb.z += __shfl_xor(qb.z, off, 64); qb.w += __shfl_xor(qb.w, off, 64);
    }
    if ((tid & 63) < 16) {
        atomicAdd(&sSum[ca + 0], sa.x); atomicAdd(&sSum[ca + 1], sa.y);
        atomicAdd(&sSum[ca + 2], sa.z); atomicAdd(&sSum[ca + 3], sa.w);
        atomicAdd(&sSum[cb + 0], sb.x); atomicAdd(&sSum[cb + 1], sb.y);
        atomicAdd(&sSum[cb + 2], sb.z); atomicAdd(&sSum[cb + 3], sb.w);
        atomicAdd(&sSum[128 + ca + 0], qa.x); atomicAdd(&sSum[128 + ca + 1], qa.y);
        atomicAdd(&sSum[128 + ca + 2], qa.z); atomicAdd(&sSum[128 + ca + 3], qa.w);
        atomicAdd(&sSum[128 + cb + 0], qb.x); atomicAdd(&sSum[128 + cb + 1], qb.y);
        atomicAdd(&sSum[128 + cb + 2], qb.z); atomicAdd(&sSum[128 + cb + 3], qb.w);
    }
    __syncthreads();
    atomicAdd(&sums[tid], sSum[tid]);   // sums layout: [s(128) | s2(128)]
}

// ---------------- BatchNorm normalize (final layer only) ----------------
__global__ __launch_bounds__(256) void k_bn(const float* __restrict__ h2,
                                            const float* __restrict__ sums,
                                            const float* __restrict__ gamma,
                                            const float* __restrict__ beta,
                                            float* __restrict__ out) {
    const int t = blockIdx.x * 256 + threadIdx.x;  // NN*32 threads
    const size_t base = (size_t)t * 4;
    const int c = (int)(base & 127);
    const float4 v = *(const float4*)(h2 + base);
    const float4 s = *(const float4*)(sums + c);
    const float4 s2 = *(const float4*)(sums + DD + c);
    const float4 g = *(const float4*)(gamma + c);
    const float4 b = *(const float4*)(beta + c);
    const float invN = 1.0f / (float)NN;
    float4 o;
    {
        float mu = s.x * invN; float var = s2.x * invN - mu * mu;
        o.x = (v.x - mu) * (g.x * rsqrtf(var + EPS)) + b.x;
    }
    {
        float mu = s.y * invN; float var = s2.y * invN - mu * mu;
        o.y = (v.y - mu) * (g.y * rsqrtf(var + EPS)) + b.y;
    }
    {
        float mu = s.z * invN; float var = s2.z * invN - mu * mu;
        o.z = (v.z - mu) * (g.z * rsqrtf(var + EPS)) + b.z;
    }
    {
        float mu = s.w * invN; float var = s2.w * invN - mu * mu;
        o.w = (v.w - mu) * (g.w * rsqrtf(var + EPS)) + b.w;
    }
    *(float4*)(out + base) = o;
}

extern "C" void kernel_launch(void* const* d_in, const int* in_sizes, int n_in,
                              void* d_out, int out_size, void* d_ws, size_t ws_size,
                              hipStream_t stream) {
    const float* X     = (const float*)d_in[0];
    const int*   src   = (const int*)d_in[1];
    const int*   dst   = (const int*)d_in[2];
    const float* Wi    = (const float*)d_in[3];
    const float* Wg    = (const float*)d_in[4];
    const float* bg    = (const float*)d_in[5];
    const float* Wr    = (const float*)d_in[6];
    const float* br    = (const float*)d_in[7];
    const float* gamma = (const float*)d_in[8];
    const float* beta  = (const float*)d_in[9];
    float* out = (float*)d_out;

    float* h    = (float*)d_ws;                       // [NN*DD]
    float* agg  = h + (size_t)NN * DD;                // [NN*DD]
    float* sums = agg + (size_t)NN * DD;              // [NL*2*DD]
    float* abv  = sums + NL * 2 * DD;                 // [NL*2*DD]  a/b per layer input
    int* rowptr = (int*)(abv + NL * 2 * DD);          // [NN+1]
    int* col    = rowptr + NN + 1;                    // [NE]
    int* bsum   = col + NE;                           // [NB]
    int* boff   = bsum + NB;                          // [NB]
    // CSR-build scratch aliased into agg (dead once k_fill completes)
    int* cnt    = (int*)agg;                          // [NN]
    int* offs   = cnt + NN;                           // [NN]

    hipMemsetAsync(sums, 0, NL * 2 * DD * sizeof(float), stream);
    hipMemsetAsync(cnt, 0, NN * sizeof(int), stream);

    k_prep<<<1, 256, 0, stream>>>(abv);               // identity a=1,b=0 for layer 0
    k_init<<<NN / 64, 64, 0, stream>>>(X, Wi, h);
    k_hist<<<NE / 256, 256, 0, stream>>>(dst, cnt);
    k_scan1<<<NB, 256, 0, stream>>>(cnt, bsum);
    k_scan2<<<1, 512, 0, stream>>>(bsum, boff);
    k_scan3<<<NB, 256, 0, stream>>>(cnt, boff, rowptr, offs);
    k_fill<<<NE / 256, 256, 0, stream>>>(src, dst, offs, col);

    // raw-activation buffers alternate: h -> out -> h -> out (final BN in-place on out)
    const float* hcur = h;
    float* h2bufs[NL] = { out, h, out };
    for (int l = 0; l < NL; ++l) {
        const float* abl = abv + l * 2 * DD;
        float* h2 = h2bufs[l];
        k_gather<<<NN / 4, 256, 0, stream>>>(hcur, rowptr, col, abl, agg);
        k_layer<<<NN / 128, 256, 0, stream>>>(hcur, agg,
                                              Wg + l * DD * DD, bg + l * DD,
                                              Wr + l * DD * DD, br + l * DD,
                                              abl, h2, sums + l * 2 * DD);
        if (l < NL - 1) {
            k_stats<<<1, 128, 0, stream>>>(sums + l * 2 * DD, gamma + l * DD,
                                           beta + l * DD, abv + (l + 1) * 2 * DD);
        } else {
            k_bn<<<(NN * 32) / 256, 256, 0, stream>>>(h2, sums + l * 2 * DD,
                                                      gamma + l * DD, beta + l * DD, out);
        }
        hcur = h2;
    }
}

// Round 9
// 513.860 us; speedup vs baseline: 9.5949x; 1.2212x over previous
//
#include <hip/hip_runtime.h>

#define NN 74240      // nodes
#define NE 593920     // edges
#define DIN 75
#define DD 128
#define NL 3
#define EPS 1e-5f
#define NB 290        // scan blocks: 290*256 == NN

typedef __attribute__((ext_vector_type(8))) short short8;   // 8 bf16 = 4 VGPRs (MFMA A/B frag)
typedef __attribute__((ext_vector_type(4))) float f32x4;    // MFMA C/D frag

// fp32 -> bf16 with round-to-nearest-even
static __device__ __forceinline__ unsigned short f2bf(float f) {
    union { float f; unsigned u; } v; v.f = f;
    unsigned u = v.u;
    unsigned r = (u + 0x7fffu + ((u >> 16) & 1u)) >> 16;
    return (unsigned short)r;
}

// ---------------- init GEMM: h = X @ W_init  ([NN,75] @ [75,128]) ----------------
__global__ __launch_bounds__(64) void k_init(const float* __restrict__ X,
                                             const float* __restrict__ W,
                                             float* __restrict__ h) {
    __shared__ float sX[64 * 77];
    const int r0 = blockIdx.x * 64;
    const int lane = threadIdx.x;
    const float* Xb = X + (size_t)r0 * DIN;
    for (int e = lane; e < 64 * DIN; e += 64) {
        int r = e / DIN;
        int k = e - r * DIN;
        sX[r * 77 + k] = Xb[e];
    }
    __syncthreads();
    float* hrow = h + (size_t)(r0 + lane) * DD;
    const float* xr = &sX[lane * 77];
    for (int ct = 0; ct < 8; ++ct) {
        const int c0 = ct * 16;
        float acc[16];
        #pragma unroll
        for (int j = 0; j < 16; ++j) acc[j] = 0.0f;
        #pragma unroll 5
        for (int k = 0; k < DIN; ++k) {
            const float a = xr[k];
            const float* wk = W + k * DD + c0;
            #pragma unroll
            for (int j = 0; j < 16; ++j)
                acc[j] = fmaf(a, wk[j], acc[j]);
        }
        #pragma unroll
        for (int j = 0; j < 16; ++j) hrow[c0 + j] = acc[j];
    }
}

// ---------------- weight prepack: fp32 [k][n] -> frag-ordered bf16 ----------------
// frag flat index: ((s*8 + t)*64 + (q*16 + (n&15)))*8 + j  with s=k/32, q=(k/8)%4, j=k%8, t=n/16
// -> each lane's B-frag is one contiguous 16B chunk (conflict-free ds_read_b128).
__global__ __launch_bounds__(256) void k_wprep(const float* __restrict__ Wg,
                                               const float* __restrict__ Wr,
                                               unsigned short* __restrict__ wf) {
    const int tid = blockIdx.x * 256 + threadIdx.x;   // grid*256 == NL*2*16384
    const int l = tid >> 15;
    const int m = (tid >> 14) & 1;
    const int e = tid & 16383;
    const int k = e >> 7, n = e & 127;
    const float* W = (m == 0 ? Wg : Wr) + l * 16384;
    const float v = W[e];
    const int s = k >> 5, q = (k >> 3) & 3, j = k & 7, t = n >> 4;
    const int ln = (q << 4) | (n & 15);
    const int idx = ((s * 8 + t) * 64 + ln) * 8 + j;
    wf[(l * 2 + m) * 16384 + idx] = f2bf(v);
}

// ---------------- CSR build: histogram -> 3-phase scan -> fill ----------------
__global__ __launch_bounds__(256) void k_hist(const int* __restrict__ dst, int* cnt) {
    const int e = blockIdx.x * 256 + threadIdx.x;   // grid == NE
    atomicAdd(&cnt[dst[e]], 1);
}

__global__ __launch_bounds__(256) void k_scan1(const int* __restrict__ cnt,
                                               int* __restrict__ bsum) {
    const int tid = threadIdx.x;
    int v = cnt[blockIdx.x * 256 + tid];
    #pragma unroll
    for (int off = 1; off < 64; off <<= 1) v += __shfl_xor(v, off, 64);
    __shared__ int ws[4];
    if ((tid & 63) == 0) ws[tid >> 6] = v;
    __syncthreads();
    if (tid == 0) bsum[blockIdx.x] = ws[0] + ws[1] + ws[2] + ws[3];
}

__global__ __launch_bounds__(512) void k_scan2(const int* __restrict__ bsum,
                                               int* __restrict__ boff) {
    __shared__ int s[512];
    const int t = threadIdx.x;
    const int v = (t < NB) ? bsum[t] : 0;
    s[t] = v;
    __syncthreads();
    for (int off = 1; off < 512; off <<= 1) {
        const int u = (t >= off) ? s[t - off] : 0;
        __syncthreads();
        s[t] += u;
        __syncthreads();
    }
    if (t < NB) boff[t] = s[t] - v;   // exclusive
}

__global__ __launch_bounds__(256) void k_scan3(const int* __restrict__ cnt,
                                               const int* __restrict__ boff,
                                               int* __restrict__ rowptr,
                                               int* __restrict__ offs) {
    const int tid = threadIdx.x;
    const int t = blockIdx.x * 256 + tid;
    const int lane = tid & 63;
    const int v = cnt[t];
    int inc = v;
    #pragma unroll
    for (int off = 1; off < 64; off <<= 1) {
        const int u = __shfl_up(inc, off, 64);
        if (lane >= off) inc += u;
    }
    __shared__ int ws[4];
    if (lane == 63) ws[tid >> 6] = inc;
    __syncthreads();
    const int w = tid >> 6;
    int waveoff = 0;
    for (int i = 0; i < 4; ++i) waveoff += (i < w) ? ws[i] : 0;
    const int excl = boff[blockIdx.x] + waveoff + inc - v;
    rowptr[t] = excl;
    offs[t] = excl;
    if (blockIdx.x == NB - 1 && tid == 255) rowptr[NN] = NE;
}

__global__ __launch_bounds__(256) void k_fill(const int* __restrict__ src,
                                              const int* __restrict__ dst,
                                              int* offs, int* __restrict__ col) {
    const int e = blockIdx.x * 256 + threadIdx.x;   // grid == NE
    const int pos = atomicAdd(&offs[dst[e]], 1);
    col[pos] = src[e];
}

// ---------------- BN affine-coefficient helpers ----------------
__global__ __launch_bounds__(256) void k_prep(float* __restrict__ ab0) {
    ab0[threadIdx.x] = (threadIdx.x < 128) ? 1.0f : 0.0f;   // identity for layer 0 input
}

__global__ __launch_bounds__(128) void k_stats(const float* __restrict__ sums,
                                               const float* __restrict__ gamma,
                                               const float* __restrict__ beta,
                                               float* __restrict__ ab) {
    const int c = threadIdx.x;
    const float invN = 1.0f / (float)NN;
    const float mu = sums[c] * invN;
    const float var = sums[128 + c] * invN - mu * mu;
    const float a = gamma[c] * rsqrtf(var + EPS);
    ab[c] = a;
    ab[128 + c] = beta[c] - a * mu;
}

// ---------------- gather (BN folded): agg[row] = a * sum_e h_raw[col[e]] + deg*b ----
__global__ __launch_bounds__(256) void k_gather(const float* __restrict__ h,
                                                const int* __restrict__ rowptr,
                                                const int* __restrict__ col,
                                                const float* __restrict__ ab,
                                                float* __restrict__ agg) {
    const int wave = threadIdx.x >> 6;
    const int lane = threadIdx.x & 63;
    const int row = blockIdx.x * 4 + wave;   // grid = NN/4
    const int eb = rowptr[row];
    const int ee = rowptr[row + 1];
    const int half = lane >> 5;
    const int f = (lane & 31) * 4;
    float4 a0 = {0.f,0.f,0.f,0.f}, a1 = {0.f,0.f,0.f,0.f};
    float4 a2 = {0.f,0.f,0.f,0.f}, a3 = {0.f,0.f,0.f,0.f};
    int e = eb + half;
    for (; e + 6 < ee; e += 8) {
        const int c0 = col[e], c1 = col[e + 2], c2 = col[e + 4], c3 = col[e + 6];
        const float4 v0 = *(const float4*)(h + (size_t)c0 * DD + f);
        const float4 v1 = *(const float4*)(h + (size_t)c1 * DD + f);
        const float4 v2 = *(const float4*)(h + (size_t)c2 * DD + f);
        const float4 v3 = *(const float4*)(h + (size_t)c3 * DD + f);
        a0.x += v0.x; a0.y += v0.y; a0.z += v0.z; a0.w += v0.w;
        a1.x += v1.x; a1.y += v1.y; a1.z += v1.z; a1.w += v1.w;
        a2.x += v2.x; a2.y += v2.y; a2.z += v2.z; a2.w += v2.w;
        a3.x += v3.x; a3.y += v3.y; a3.z += v3.z; a3.w += v3.w;
    }
    for (; e < ee; e += 2) {
        const int c = col[e];
        const float4 v = *(const float4*)(h + (size_t)c * DD + f);
        a0.x += v.x; a0.y += v.y; a0.z += v.z; a0.w += v.w;
    }
    float4 s;
    s.x = (a0.x + a1.x) + (a2.x + a3.x);
    s.y = (a0.y + a1.y) + (a2.y + a3.y);
    s.z = (a0.z + a1.z) + (a2.z + a3.z);
    s.w = (a0.w + a1.w) + (a2.w + a3.w);
    s.x += __shfl_xor(s.x, 32, 64);
    s.y += __shfl_xor(s.y, 32, 64);
    s.z += __shfl_xor(s.z, 32, 64);
    s.w += __shfl_xor(s.w, 32, 64);
    if (half == 0) {
        const float deg = (float)(ee - eb);
        const float4 av = *(const float4*)(ab + f);
        const float4 bv = *(const float4*)(ab + 128 + f);
        float4 o;
        o.x = fmaf(av.x, s.x, deg * bv.x);
        o.y = fmaf(av.y, s.y, deg * bv.y);
        o.z = fmaf(av.z, s.z, deg * bv.z);
        o.w = fmaf(av.w, s.w, deg * bv.w);
        *(float4*)(agg + (size_t)row * DD + f) = o;
    }
}

// ---------------- fused layer GEMMs via bf16 MFMA ----------------
// Block: 64 rows (4 waves x 16-row M-tile), full 128 cols. K=128 in 4 steps of 32.
// Weights: frag-ordered bf16 in LDS (b128 lane-contiguous reads, conflict-free).
// A (agg, BN pre-folded) and H (BN affine applied here) frags loaded DIRECT from
// global fp32 (16 rows x 128B chunks, L2/HBM), converted to bf16 in registers.
// Layouts (m89/m91/m120-verified): A-op [m=lane&15][k=q*8+j]; B-op [k=q*8+j][n=lane&15];
// C/D col=lane&15, row=q*4+reg.
__global__ __launch_bounds__(256, 2) void k_layer(const float* __restrict__ hin,
                                                  const float* __restrict__ aggin,
                                                  const unsigned short* __restrict__ wfrag,
                                                  const float* __restrict__ bg,
                                                  const float* __restrict__ br,
                                                  const float* __restrict__ ab,
                                                  float* __restrict__ h2out,
                                                  float* sums) {
    __shared__ unsigned short sBg[16384];   // 32 KB, frag-ordered Wg
    __shared__ unsigned short sBr[16384];   // 32 KB, frag-ordered Wr
    __shared__ float sSum[256];
    const int tid = threadIdx.x;

    {   // stage both weight-frag arrays (coalesced b128 copies)
        const uint4* srcg = (const uint4*)wfrag;          // 2048 uint4
        const uint4* srcr = srcg + 2048;
        uint4* dg = (uint4*)sBg;
        uint4* dr = (uint4*)sBr;
        #pragma unroll
        for (int i = 0; i < 8; ++i) dg[tid + i * 256] = srcg[tid + i * 256];
        #pragma unroll
        for (int i = 0; i < 8; ++i) dr[tid + i * 256] = srcr[tid + i * 256];
        sSum[tid] = 0.0f;
    }
    __syncthreads();

    const int w = tid >> 6;          // wave 0..3
    const int lane = tid & 63;
    const int ln15 = lane & 15;
    const int q = lane >> 4;
    const int r0 = blockIdx.x * 64 + w * 16;   // wave's 16-row M-tile base
    const int arow = r0 + ln15;                // row this lane's A/H frag holds

    f32x4 accg[8], accr[8];
    #pragma unroll
    for (int t = 0; t < 8; ++t) {
        accg[t] = (f32x4){0.f, 0.f, 0.f, 0.f};
        accr[t] = (f32x4){0.f, 0.f, 0.f, 0.f};
    }

    #pragma unroll
    for (int s = 0; s < 4; ++s) {
        const int kk = s * 32 + q * 8;
        const float4 a0 = *(const float4*)(aggin + (size_t)arow * DD + kk);
        const float4 a1 = *(const float4*)(aggin + (size_t)arow * DD + kk + 4);
        const float4 h0 = *(const float4*)(hin + (size_t)arow * DD + kk);
        const float4 h1 = *(const float4*)(hin + (size_t)arow * DD + kk + 4);
        const float4 av0 = *(const float4*)(ab + kk);
        const float4 av1 = *(const float4*)(ab + kk + 4);
        const float4 bv0 = *(const float4*)(ab + 128 + kk);
        const float4 bv1 = *(const float4*)(ab + 128 + kk + 4);
        short8 af, hf;
        af[0] = (short)f2bf(a0.x); af[1] = (short)f2bf(a0.y);
        af[2] = (short)f2bf(a0.z); af[3] = (short)f2bf(a0.w);
        af[4] = (short)f2bf(a1.x); af[5] = (short)f2bf(a1.y);
        af[6] = (short)f2bf(a1.z); af[7] = (short)f2bf(a1.w);
        hf[0] = (short)f2bf(fmaf(av0.x, h0.x, bv0.x));
        hf[1] = (short)f2bf(fmaf(av0.y, h0.y, bv0.y));
        hf[2] = (short)f2bf(fmaf(av0.z, h0.z, bv0.z));
        hf[3] = (short)f2bf(fmaf(av0.w, h0.w, bv0.w));
        hf[4] = (short)f2bf(fmaf(av1.x, h1.x, bv1.x));
        hf[5] = (short)f2bf(fmaf(av1.y, h1.y, bv1.y));
        hf[6] = (short)f2bf(fmaf(av1.z, h1.z, bv1.z));
        hf[7] = (short)f2bf(fmaf(av1.w, h1.w, bv1.w));
        const int fb = s * 4096;   // frag base for this k-step
        #pragma unroll
        for (int t = 0; t < 8; ++t) {
            const short8 bgf = *(const short8*)&sBg[fb + (t * 64 + lane) * 8];
            const short8 brf = *(const short8*)&sBr[fb + (t * 64 + lane) * 8];
            accg[t] = __builtin_amdgcn_mfma_f32_16x16x32_bf16(af, bgf, accg[t], 0, 0, 0);
            accr[t] = __builtin_amdgcn_mfma_f32_16x16x32_bf16(hf, brf, accr[t], 0, 0, 0);
        }
    }

    // epilogue: bias + relu + add, store h2, fused BN partial sums
    #pragma unroll
    for (int t = 0; t < 8; ++t) {
        const int c = t * 16 + ln15;
        const float bgc = bg[c];
        const float brc = br[c];
        float sv = 0.f, qv = 0.f;
        #pragma unroll
        for (int r = 0; r < 4; ++r) {
            const int row = r0 + q * 4 + r;
            const float v = fmaxf(accg[t][r] + bgc, 0.f) + fmaxf(accr[t][r] + brc, 0.f);
            h2out[(size_t)row * DD + c] = v;
            sv += v; qv += v * v;
        }
        sv += __shfl_xor(sv, 16, 64); sv += __shfl_xor(sv, 32, 64);
        qv += __shfl_xor(qv, 16, 64); qv += __shfl_xor(qv, 32, 64);
        if (q == 0) {
            atomicAdd(&sSum[c], sv);
            atomicAdd(&sSum[128 + c], qv);
        }
    }
    __syncthreads();
    atomicAdd(&sums[tid], sSum[tid]);   // sums layout: [s(128) | s2(128)]
}

// ---------------- BatchNorm normalize (final layer only) ----------------
__global__ __launch_bounds__(256) void k_bn(const float* __restrict__ h2,
                                            const float* __restrict__ sums,
                                            const float* __restrict__ gamma,
                                            const float* __restrict__ beta,
                                            float* __restrict__ out) {
    const int t = blockIdx.x * 256 + threadIdx.x;  // NN*32 threads
    const size_t base = (size_t)t * 4;
    const int c = (int)(base & 127);
    const float4 v = *(const float4*)(h2 + base);
    const float4 s = *(const float4*)(sums + c);
    const float4 s2 = *(const float4*)(sums + DD + c);
    const float4 g = *(const float4*)(gamma + c);
    const float4 b = *(const float4*)(beta + c);
    const float invN = 1.0f / (float)NN;
    float4 o;
    {
        float mu = s.x * invN; float var = s2.x * invN - mu * mu;
        o.x = (v.x - mu) * (g.x * rsqrtf(var + EPS)) + b.x;
    }
    {
        float mu = s.y * invN; float var = s2.y * invN - mu * mu;
        o.y = (v.y - mu) * (g.y * rsqrtf(var + EPS)) + b.y;
    }
    {
        float mu = s.z * invN; float var = s2.z * invN - mu * mu;
        o.z = (v.z - mu) * (g.z * rsqrtf(var + EPS)) + b.z;
    }
    {
        float mu = s.w * invN; float var = s2.w * invN - mu * mu;
        o.w = (v.w - mu) * (g.w * rsqrtf(var + EPS)) + b.w;
    }
    *(float4*)(out + base) = o;
}

extern "C" void kernel_launch(void* const* d_in, const int* in_sizes, int n_in,
                              void* d_out, int out_size, void* d_ws, size_t ws_size,
                              hipStream_t stream) {
    const float* X     = (const float*)d_in[0];
    const int*   src   = (const int*)d_in[1];
    const int*   dst   = (const int*)d_in[2];
    const float* Wi    = (const float*)d_in[3];
    const float* Wg    = (const float*)d_in[4];
    const float* bg    = (const float*)d_in[5];
    const float* Wr    = (const float*)d_in[6];
    const float* br    = (const float*)d_in[7];
    const float* gamma = (const float*)d_in[8];
    const float* beta  = (const float*)d_in[9];
    float* out = (float*)d_out;

    float* h    = (float*)d_ws;                       // [NN*DD]
    float* agg  = h + (size_t)NN * DD;                // [NN*DD]
    float* sums = agg + (size_t)NN * DD;              // [NL*2*DD]
    float* abv  = sums + NL * 2 * DD;                 // [NL*2*DD]  a/b per layer input
    unsigned short* wfrag = (unsigned short*)(abv + NL * 2 * DD);  // [NL*2*16384] bf16 frags (16B-aligned)
    int* rowptr = (int*)(wfrag + NL * 2 * 16384);     // [NN+1]
    int* col    = rowptr + NN + 1;                    // [NE]
    int* bsum   = col + NE;                           // [NB]
    int* boff   = bsum + NB;                          // [NB]
    // CSR-build scratch aliased into agg (dead once k_fill completes)
    int* cnt    = (int*)agg;                          // [NN]
    int* offs   = cnt + NN;                           // [NN]

    hipMemsetAsync(sums, 0, NL * 2 * DD * sizeof(float), stream);
    hipMemsetAsync(cnt, 0, NN * sizeof(int), stream);

    k_prep<<<1, 256, 0, stream>>>(abv);               // identity a=1,b=0 for layer 0
    k_init<<<NN / 64, 64, 0, stream>>>(X, Wi, h);
    k_wprep<<<(NL * 2 * 16384) / 256, 256, 0, stream>>>(Wg, Wr, wfrag);
    k_hist<<<NE / 256, 256, 0, stream>>>(dst, cnt);
    k_scan1<<<NB, 256, 0, stream>>>(cnt, bsum);
    k_scan2<<<1, 512, 0, stream>>>(bsum, boff);
    k_scan3<<<NB, 256, 0, stream>>>(cnt, boff, rowptr, offs);
    k_fill<<<NE / 256, 256, 0, stream>>>(src, dst, offs, col);

    // raw-activation buffers alternate: h -> out -> h -> out (final BN in-place on out)
    const float* hcur = h;
    float* h2bufs[NL] = { out, h, out };
    for (int l = 0; l < NL; ++l) {
        const float* abl = abv + l * 2 * DD;
        float* h2 = h2bufs[l];
        k_gather<<<NN / 4, 256, 0, stream>>>(hcur, rowptr, col, abl, agg);
        k_layer<<<NN / 64, 256, 0, stream>>>(hcur, agg,
                                             wfrag + l * 2 * 16384,
                                             bg + l * DD, br + l * DD,
                                             abl, h2, sums + l * 2 * DD);
        if (l < NL - 1) {
            k_stats<<<1, 128, 0, stream>>>(sums + l * 2 * DD, gamma + l * DD,
                                           beta + l * DD, abv + (l + 1) * 2 * DD);
        } else {
            k_bn<<<(NN * 32) / 256, 256, 0, stream>>>(h2, sums + l * 2 * DD,
                                                      gamma + l * DD, beta + l * DD, out);
        }
        hcur = h2;
    }
}